// Round 3
// baseline (1132.044 us; speedup 1.0000x reference)
//
#include <hip/hip_runtime.h>

typedef unsigned short ushort_t;
typedef unsigned int   uint_t;

// bf16 helpers for the FS/FD scratch arrays (stored bf16, computed f32)
__device__ __forceinline__ float bl(uint_t u){ return __uint_as_float(u<<16); }
__device__ __forceinline__ float bh(uint_t u){ return __uint_as_float(u & 0xffff0000u); }
__device__ __forceinline__ ushort_t f2b(float f){
  uint_t x = __float_as_uint(f);
  return (ushort_t)((x + 0x7fffu + ((x>>16)&1u)) >> 16);   // RTNE
}
__device__ __forceinline__ uint_t pack2(float a, float b){
  return (uint_t)f2b(a) | ((uint_t)f2b(b) << 16);
}

// ---------------- zeroing ----------------
__global__ void k_zero(int* __restrict__ p, int n){
  int i = blockIdx.x*256 + threadIdx.x;
  if (i < n) p[i] = 0;
}

// ---------------- CSR build ----------------
__global__ void k_hist(const int* __restrict__ dst, int* __restrict__ deg, int E){
  for (int i = blockIdx.x*blockDim.x + threadIdx.x; i < E; i += gridDim.x*blockDim.x)
    atomicAdd(&deg[dst[i]], 1);
}

__global__ __launch_bounds__(1024) void k_scan(const int* __restrict__ deg,
                                               int* __restrict__ rowp, int n){
  __shared__ int sums[1024];
  int tid = threadIdx.x;
  int chunk = (n + 1023) >> 10;
  int start = tid * chunk;
  int end = start + chunk; if (end > n) end = n; if (start > n) start = n;
  int local = 0;
  for (int i = start; i < end; ++i) local += deg[i];
  sums[tid] = local;
  __syncthreads();
  for (int off = 1; off < 1024; off <<= 1) {
    int v = (tid >= off) ? sums[tid - off] : 0;
    __syncthreads();
    sums[tid] += v;
    __syncthreads();
  }
  int run = (tid == 0) ? 0 : sums[tid - 1];
  for (int i = start; i < end; ++i) { rowp[i] = run; run += deg[i]; }
  if (end == n) rowp[n] = run;
}

__global__ void k_scatter(const int* __restrict__ src, const int* __restrict__ dst,
                          const int* __restrict__ rowp, int* __restrict__ cnt,
                          int* __restrict__ csrc, int E){
  for (int i = blockIdx.x*blockDim.x + threadIdx.x; i < E; i += gridDim.x*blockDim.x) {
    int d = dst[i];
    int p = rowp[d] + atomicAdd(&cnt[d], 1);
    csrc[p] = src[i];
  }
}

// ------- input GEMM: H = nf @ W_in + b_in  (f32, K=64 -> 128 cols) -----------
__global__ __launch_bounds__(256) void k_gemm_in(
    const float* __restrict__ nf, const float* __restrict__ W,
    const float* __restrict__ b, float* __restrict__ H, int N)
{
  __shared__ float sA[64*64];
  int row0 = blockIdx.x * 64;
  int tid = threadIdx.x;
  {
    int q = tid;                      // 1024 float4 total, 256 threads x 4
    #pragma unroll
    for (int j = 0; j < 4; ++j, q += 256) {
      int r = q >> 4;
      int c = (q & 15) << 2;
      float4 v = make_float4(0.f,0.f,0.f,0.f);
      if (row0 + r < N) v = *(const float4*)&nf[(size_t)(row0 + r)*64 + c];
      *(float4*)&sA[r*64 + c] = v;
    }
  }
  __syncthreads();
  int cg = tid & 15, rg = tid >> 4;   // 16 col-groups x 8 cols, 16 row-groups x 4 rows
  int c0 = cg * 8;
  float acc[4][8];
  #pragma unroll
  for (int i = 0; i < 4; ++i)
    #pragma unroll
    for (int j = 0; j < 8; ++j) acc[i][j] = 0.f;
  for (int k = 0; k < 64; ++k) {
    float4 wa = *(const float4*)&W[k*128 + c0];
    float4 wb = *(const float4*)&W[k*128 + c0 + 4];
    float w[8] = {wa.x,wa.y,wa.z,wa.w,wb.x,wb.y,wb.z,wb.w};
    float hv[4];
    #pragma unroll
    for (int i = 0; i < 4; ++i) hv[i] = sA[(rg*4 + i)*64 + k];
    #pragma unroll
    for (int i = 0; i < 4; ++i)
      #pragma unroll
      for (int j = 0; j < 8; ++j) acc[i][j] += hv[i]*w[j];
  }
  float4 b1 = *(const float4*)&b[c0];
  float4 b2 = *(const float4*)&b[c0 + 4];
  float bb[8] = {b1.x,b1.y,b1.z,b1.w,b2.x,b2.y,b2.z,b2.w};
  #pragma unroll
  for (int i = 0; i < 4; ++i) {
    int row = row0 + rg*4 + i;
    if (row < N) {
      #pragma unroll
      for (int j = 0; j < 8; j += 4) {
        float4 o = make_float4(acc[i][j]+bb[j], acc[i][j+1]+bb[j+1],
                               acc[i][j+2]+bb[j+2], acc[i][j+3]+bb[j+3]);
        *(float4*)&H[(size_t)row*128 + c0 + j] = o;
      }
    }
  }
}

// ------- layer GEMM: FS/FD = bf16( H @ W_src|W_dst + b )  (K=128) ------------
__global__ __launch_bounds__(256) void k_gemm_layer(
    const float* __restrict__ H,
    const float* __restrict__ Wsrc, const float* __restrict__ Wdst,
    const float* __restrict__ bsrc, const float* __restrict__ bdst,
    ushort_t* __restrict__ FS, ushort_t* __restrict__ FD, int N)
{
  __shared__ float sA[64*128];
  int row0 = blockIdx.x * 64;
  int tid = threadIdx.x;
  {
    int q = tid;                      // 2048 float4 total, 256 threads x 8
    #pragma unroll
    for (int j = 0; j < 8; ++j, q += 256) {
      int r = q >> 5;
      int c = (q & 31) << 2;
      float4 v = make_float4(0.f,0.f,0.f,0.f);
      if (row0 + r < N) v = *(const float4*)&H[(size_t)(row0 + r)*128 + c];
      *(float4*)&sA[r*128 + c] = v;
    }
  }
  __syncthreads();
  int cg = tid & 31, rg = tid >> 5;   // 32 col-groups x 8 cols (256), 8 row-groups x 8 rows
  int c0 = cg * 8;
  const float* W   = (c0 < 128) ? Wsrc : Wdst;
  const float* B   = (c0 < 128) ? bsrc : bdst;
  ushort_t*    OUT = (c0 < 128) ? FS   : FD;
  int cc = c0 & 127;
  float acc[8][8];
  #pragma unroll
  for (int i = 0; i < 8; ++i)
    #pragma unroll
    for (int j = 0; j < 8; ++j) acc[i][j] = 0.f;
  for (int k = 0; k < 128; ++k) {
    float4 wa = *(const float4*)&W[k*128 + cc];
    float4 wb = *(const float4*)&W[k*128 + cc + 4];
    float w[8] = {wa.x,wa.y,wa.z,wa.w,wb.x,wb.y,wb.z,wb.w};
    float hv[8];
    #pragma unroll
    for (int i = 0; i < 8; ++i) hv[i] = sA[(rg*8 + i)*128 + k];
    #pragma unroll
    for (int i = 0; i < 8; ++i)
      #pragma unroll
      for (int j = 0; j < 8; ++j) acc[i][j] += hv[i]*w[j];
  }
  float4 b1 = *(const float4*)&B[cc];
  float4 b2 = *(const float4*)&B[cc + 4];
  float bb[8] = {b1.x,b1.y,b1.z,b1.w,b2.x,b2.y,b2.z,b2.w};
  #pragma unroll
  for (int i = 0; i < 8; ++i) {
    int row = row0 + rg*8 + i;
    if (row < N) {
      uint4 o;
      o.x = pack2(acc[i][0]+bb[0], acc[i][1]+bb[1]);
      o.y = pack2(acc[i][2]+bb[2], acc[i][3]+bb[3]);
      o.z = pack2(acc[i][4]+bb[4], acc[i][5]+bb[5]);
      o.w = pack2(acc[i][6]+bb[6], acc[i][7]+bb[7]);
      *(uint4*)&OUT[(size_t)row*128 + cc] = o;
    }
  }
}

// ------- fused edge aggregate + softmax + residual + LN + ReLU ---------------
__global__ __launch_bounds__(256) void k_edge(
    const ushort_t* __restrict__ FS, const ushort_t* __restrict__ FD,
    float* __restrict__ H,
    const int* __restrict__ rowp, const int* __restrict__ csrc,
    const float* __restrict__ attn, const float* __restrict__ lng,
    const float* __restrict__ lnb, int N)
{
  int node = blockIdx.x * 4 + (threadIdx.x >> 6);
  if (node >= N) return;
  int lane = threadIdx.x & 63;
  int li = lane * 2;                 // li = head*32 + d; head = 16-lane group
  uint_t fdu = *(const uint_t*)&FD[(size_t)node*128 + li];
  float fd0 = bl(fdu), fd1 = bh(fdu);
  float a0 = attn[li], a1 = attn[li + 1];
  float acc0 = 0.f, acc1 = 0.f, den = 0.f;
  int beg = rowp[node], end = rowp[node + 1];
  uint_t cu = 0;
  if (beg < end) {
    int s = csrc[beg];
    cu = *(const uint_t*)&FS[(size_t)s*128 + li];
  }
  for (int k = beg; k < end; ++k) {
    uint_t nu = 0;
    if (k + 1 < end) {
      int s2 = csrc[k + 1];
      nu = *(const uint_t*)&FS[(size_t)s2*128 + li];
    }
    float c0 = bl(cu), c1 = bh(cu);
    float t0 = c0 + fd0; t0 = fmaxf(t0, 0.2f*t0);     // leaky_relu 0.2
    float t1 = c1 + fd1; t1 = fmaxf(t1, 0.2f*t1);
    float p = t0*a0 + t1*a1;
    p += __shfl_xor(p, 1);
    p += __shfl_xor(p, 2);
    p += __shfl_xor(p, 4);
    p += __shfl_xor(p, 8);           // per-head (16-lane) dot reduce
    float ex = __expf(p);            // logits O(1): max-shift unnecessary
    den  += ex;
    acc0 += ex * c0;
    acc1 += ex * c1;
    cu = nu;
  }
  float rden = (den > 0.f) ? 1.f / den : 0.f;
  float o0 = acc0 * rden, o1 = acc1 * rden;
  float2 hv = *(const float2*)&H[(size_t)node*128 + li];
  float x0 = 2.f*hv.x + o0;          // h + (out + h)
  float x1 = 2.f*hv.y + o1;
  float s = x0 + x1;
  #pragma unroll
  for (int m = 1; m < 64; m <<= 1) s += __shfl_xor(s, m);
  float mean = s * (1.f/128.f);
  float d0 = x0 - mean, d1 = x1 - mean;
  float v = d0*d0 + d1*d1;
  #pragma unroll
  for (int m = 1; m < 64; m <<= 1) v += __shfl_xor(v, m);
  float rs = rsqrtf(v * (1.f/128.f) + 1e-5f);
  float y0 = fmaxf(d0*rs*lng[li]     + lnb[li],     0.f);
  float y1 = fmaxf(d1*rs*lng[li + 1] + lnb[li + 1], 0.f);
  float2 yo = make_float2(y0, y1);
  *(float2*)&H[(size_t)node*128 + li] = yo;
}

// ---------------- pooled mean partials ----------------
__global__ __launch_bounds__(128) void k_pool(const float* __restrict__ H,
                                              float* __restrict__ pooled, int N){
  int c = threadIdx.x;
  float s = 0.f;
  for (int r = blockIdx.x; r < N; r += gridDim.x) s += H[(size_t)r*128 + c];
  atomicAdd(&pooled[c], s);
}

// ---------------- final head ----------------
__global__ __launch_bounds__(256) void k_final(
    const float* __restrict__ gf, const float* __restrict__ pooled,
    const float* __restrict__ Wg, const float* __restrict__ bg,
    const float* __restrict__ Wf1, const float* __restrict__ bf1,
    const float* __restrict__ Wf2, const float* __restrict__ bf2v,
    float* __restrict__ out, float inv_n)
{
  __shared__ float comb[256];
  __shared__ float t1[128];
  int tid = threadIdx.x;
  if (tid < 128) {
    comb[tid] = pooled[tid] * inv_n;
  } else {
    int c = tid - 128;
    float s = bg[c];
    for (int k = 0; k < 32; ++k) s += gf[k] * Wg[k*128 + c];
    comb[128 + c] = s;
  }
  __syncthreads();
  if (tid < 128) {
    float s = bf1[tid];
    for (int k = 0; k < 256; ++k) s += comb[k] * Wf1[k*128 + tid];
    t1[tid] = fmaxf(s, 0.f);
  }
  __syncthreads();
  if (tid < 128) {
    float s = bf2v[tid];
    for (int k = 0; k < 128; ++k) s += t1[k] * Wf2[k*128 + tid];
    out[tid] = s;
  }
}

// ---------------- launch ----------------
extern "C" void kernel_launch(void* const* d_in, const int* in_sizes, int n_in,
                              void* d_out, int out_size, void* d_ws, size_t ws_size,
                              hipStream_t stream) {
  const float* node_feats = (const float*)d_in[0];
  const float* graph_feats= (const float*)d_in[1];
  const int*   src        = (const int*)d_in[2];
  const int*   dst        = (const int*)d_in[3];
  const float* W_in  = (const float*)d_in[4];
  const float* b_in  = (const float*)d_in[5];
  const float* W_g   = (const float*)d_in[6];
  const float* b_g   = (const float*)d_in[7];
  const float* W_src = (const float*)d_in[8];
  const float* b_src = (const float*)d_in[9];
  const float* W_dst = (const float*)d_in[10];
  const float* b_dst = (const float*)d_in[11];
  const float* attn  = (const float*)d_in[12];
  const float* ln_g  = (const float*)d_in[13];
  const float* ln_b  = (const float*)d_in[14];
  const float* W_f1  = (const float*)d_in[15];
  const float* b_f1  = (const float*)d_in[16];
  const float* W_f2  = (const float*)d_in[17];
  const float* b_f2  = (const float*)d_in[18];

  int N = in_sizes[0] / 64;
  int E = in_sizes[2];

  float* out_f = (float*)d_out;
  float* GEMB  = out_f;              // [128] graph_emb
  float* H     = out_f + 128;        // [N,128] output h doubles as working buffer

  // ws layout: [pooled f32 x128 | FS bf16 N*128 | FD bf16 N*128 | ints]
  float*    pooled = (float*)d_ws;
  ushort_t* FS = (ushort_t*)((char*)d_ws + 512);
  ushort_t* FD = FS + (size_t)N * 128;
  int* ibase = (int*)(FD + (size_t)N * 128);
  int* deg  = ibase;
  int* cnt  = ibase + N;
  int* rowp = ibase + 2*N;
  int* csrc = ibase + 3*N + 1;

  k_zero<<<(2*N + 255)/256, 256, 0, stream>>>(deg, 2*N);
  k_zero<<<1, 256, 0, stream>>>((int*)pooled, 128);

  k_hist<<<2048, 256, 0, stream>>>(dst, deg, E);
  k_scan<<<1, 1024, 0, stream>>>(deg, rowp, N);
  k_scatter<<<2048, 256, 0, stream>>>(src, dst, rowp, cnt, csrc, E);

  k_gemm_in<<<(N + 63)/64, 256, 0, stream>>>(node_feats, W_in, b_in, H, N);

  for (int l = 0; l < 3; ++l) {
    k_gemm_layer<<<(N + 63)/64, 256, 0, stream>>>(
        H, W_src + l*16384, W_dst + l*16384, b_src + l*128, b_dst + l*128,
        FS, FD, N);
    k_edge<<<(N + 3)/4, 256, 0, stream>>>(
        FS, FD, H, rowp, csrc,
        attn + l*128, ln_g + l*128, ln_b + l*128, N);
  }

  k_pool<<<256, 128, 0, stream>>>(H, pooled, N);
  k_final<<<1, 256, 0, stream>>>(graph_feats, pooled, W_g, b_g, W_f1, b_f1,
                                 W_f2, b_f2, GEMB, 1.0f / (float)N);
}

// Round 4
// 858.604 us; speedup vs baseline: 1.3185x; 1.3185x over previous
//
#include <hip/hip_runtime.h>

typedef unsigned short ushort_t;
typedef unsigned int   uint_t;

// bf16 helpers for the FS/FD scratch arrays (stored bf16, computed f32)
__device__ __forceinline__ float bl(uint_t u){ return __uint_as_float(u<<16); }
__device__ __forceinline__ float bh(uint_t u){ return __uint_as_float(u & 0xffff0000u); }
__device__ __forceinline__ ushort_t f2b(float f){
  uint_t x = __float_as_uint(f);
  return (ushort_t)((x + 0x7fffu + ((x>>16)&1u)) >> 16);   // RTNE
}
__device__ __forceinline__ uint_t pack2(float a, float b){
  return (uint_t)f2b(a) | ((uint_t)f2b(b) << 16);
}

// ---------------- zeroing ----------------
__global__ void k_zero(int* __restrict__ p, int n){
  int i = blockIdx.x*256 + threadIdx.x;
  if (i < n) p[i] = 0;
}

// ---------------- CSR build ----------------
__global__ void k_hist(const int* __restrict__ dst, int* __restrict__ deg, int E){
  for (int i = blockIdx.x*blockDim.x + threadIdx.x; i < E; i += gridDim.x*blockDim.x)
    atomicAdd(&deg[dst[i]], 1);
}

__global__ __launch_bounds__(1024) void k_scan(const int* __restrict__ deg,
                                               int* __restrict__ rowp, int n){
  __shared__ int sums[1024];
  int tid = threadIdx.x;
  int chunk = (n + 1023) >> 10;
  int start = tid * chunk;
  int end = start + chunk; if (end > n) end = n; if (start > n) start = n;
  int local = 0;
  for (int i = start; i < end; ++i) local += deg[i];
  sums[tid] = local;
  __syncthreads();
  for (int off = 1; off < 1024; off <<= 1) {
    int v = (tid >= off) ? sums[tid - off] : 0;
    __syncthreads();
    sums[tid] += v;
    __syncthreads();
  }
  int run = (tid == 0) ? 0 : sums[tid - 1];
  for (int i = start; i < end; ++i) { rowp[i] = run; run += deg[i]; }
  if (end == n) rowp[n] = run;
}

__global__ void k_scatter(const int* __restrict__ src, const int* __restrict__ dst,
                          const int* __restrict__ rowp, int* __restrict__ cnt,
                          int* __restrict__ csrc, int E){
  for (int i = blockIdx.x*blockDim.x + threadIdx.x; i < E; i += gridDim.x*blockDim.x) {
    int d = dst[i];
    int p = rowp[d] + atomicAdd(&cnt[d], 1);
    csrc[p] = src[i];
  }
}

// ------- input GEMM: H = nf @ W_in + b_in  (f32, K=64 -> 128 cols) -----------
__global__ __launch_bounds__(256) void k_gemm_in(
    const float* __restrict__ nf, const float* __restrict__ W,
    const float* __restrict__ b, float* __restrict__ H, int N)
{
  __shared__ float sA[64*64];
  int row0 = blockIdx.x * 64;
  int tid = threadIdx.x;
  {
    int q = tid;                      // 1024 float4 total, 256 threads x 4
    #pragma unroll
    for (int j = 0; j < 4; ++j, q += 256) {
      int r = q >> 4;
      int c = (q & 15) << 2;
      float4 v = make_float4(0.f,0.f,0.f,0.f);
      if (row0 + r < N) v = *(const float4*)&nf[(size_t)(row0 + r)*64 + c];
      *(float4*)&sA[r*64 + c] = v;
    }
  }
  __syncthreads();
  int cg = tid & 15, rg = tid >> 4;   // 16 col-groups x 8 cols, 16 row-groups x 4 rows
  int c0 = cg * 8;
  float acc[4][8];
  #pragma unroll
  for (int i = 0; i < 4; ++i)
    #pragma unroll
    for (int j = 0; j < 8; ++j) acc[i][j] = 0.f;
  for (int k = 0; k < 64; ++k) {
    float4 wa = *(const float4*)&W[k*128 + c0];
    float4 wb = *(const float4*)&W[k*128 + c0 + 4];
    float w[8] = {wa.x,wa.y,wa.z,wa.w,wb.x,wb.y,wb.z,wb.w};
    float hv[4];
    #pragma unroll
    for (int i = 0; i < 4; ++i) hv[i] = sA[(rg*4 + i)*64 + k];
    #pragma unroll
    for (int i = 0; i < 4; ++i)
      #pragma unroll
      for (int j = 0; j < 8; ++j) acc[i][j] += hv[i]*w[j];
  }
  float4 b1 = *(const float4*)&b[c0];
  float4 b2 = *(const float4*)&b[c0 + 4];
  float bb[8] = {b1.x,b1.y,b1.z,b1.w,b2.x,b2.y,b2.z,b2.w};
  #pragma unroll
  for (int i = 0; i < 4; ++i) {
    int row = row0 + rg*4 + i;
    if (row < N) {
      #pragma unroll
      for (int j = 0; j < 8; j += 4) {
        float4 o = make_float4(acc[i][j]+bb[j], acc[i][j+1]+bb[j+1],
                               acc[i][j+2]+bb[j+2], acc[i][j+3]+bb[j+3]);
        *(float4*)&H[(size_t)row*128 + c0 + j] = o;
      }
    }
  }
}

// ------- layer GEMM: FS/FD = bf16( H @ W_src|W_dst + b )  (K=128) ------------
__global__ __launch_bounds__(256) void k_gemm_layer(
    const float* __restrict__ H,
    const float* __restrict__ Wsrc, const float* __restrict__ Wdst,
    const float* __restrict__ bsrc, const float* __restrict__ bdst,
    ushort_t* __restrict__ FS, ushort_t* __restrict__ FD, int N)
{
  __shared__ float sA[64*128];
  int row0 = blockIdx.x * 64;
  int tid = threadIdx.x;
  {
    int q = tid;                      // 2048 float4 total, 256 threads x 8
    #pragma unroll
    for (int j = 0; j < 8; ++j, q += 256) {
      int r = q >> 5;
      int c = (q & 31) << 2;
      float4 v = make_float4(0.f,0.f,0.f,0.f);
      if (row0 + r < N) v = *(const float4*)&H[(size_t)(row0 + r)*128 + c];
      *(float4*)&sA[r*128 + c] = v;
    }
  }
  __syncthreads();
  int cg = tid & 31, rg = tid >> 5;   // 32 col-groups x 8 cols (256), 8 row-groups x 8 rows
  int c0 = cg * 8;
  const float* W   = (c0 < 128) ? Wsrc : Wdst;
  const float* B   = (c0 < 128) ? bsrc : bdst;
  ushort_t*    OUT = (c0 < 128) ? FS   : FD;
  int cc = c0 & 127;
  float acc[8][8];
  #pragma unroll
  for (int i = 0; i < 8; ++i)
    #pragma unroll
    for (int j = 0; j < 8; ++j) acc[i][j] = 0.f;
  for (int k = 0; k < 128; ++k) {
    float4 wa = *(const float4*)&W[k*128 + cc];
    float4 wb = *(const float4*)&W[k*128 + cc + 4];
    float w[8] = {wa.x,wa.y,wa.z,wa.w,wb.x,wb.y,wb.z,wb.w};
    float hv[8];
    #pragma unroll
    for (int i = 0; i < 8; ++i) hv[i] = sA[(rg*8 + i)*128 + k];
    #pragma unroll
    for (int i = 0; i < 8; ++i)
      #pragma unroll
      for (int j = 0; j < 8; ++j) acc[i][j] += hv[i]*w[j];
  }
  float4 b1 = *(const float4*)&B[cc];
  float4 b2 = *(const float4*)&B[cc + 4];
  float bb[8] = {b1.x,b1.y,b1.z,b1.w,b2.x,b2.y,b2.z,b2.w};
  #pragma unroll
  for (int i = 0; i < 8; ++i) {
    int row = row0 + rg*8 + i;
    if (row < N) {
      uint4 o;
      o.x = pack2(acc[i][0]+bb[0], acc[i][1]+bb[1]);
      o.y = pack2(acc[i][2]+bb[2], acc[i][3]+bb[3]);
      o.z = pack2(acc[i][4]+bb[4], acc[i][5]+bb[5]);
      o.w = pack2(acc[i][6]+bb[6], acc[i][7]+bb[7]);
      *(uint4*)&OUT[(size_t)row*128 + cc] = o;
    }
  }
}

// ------- fused edge aggregate + softmax + residual + LN + ReLU ---------------
// 4-deep software pipeline: batch-4 row prefetch + 4 independent
// dot/shfl/exp chains per iteration (hides L2/L3 gather latency).
__global__ __launch_bounds__(256) void k_edge(
    const ushort_t* __restrict__ FS, const ushort_t* __restrict__ FD,
    float* __restrict__ H,
    const int* __restrict__ rowp, const int* __restrict__ csrc,
    const float* __restrict__ attn, const float* __restrict__ lng,
    const float* __restrict__ lnb, int N)
{
  int node = blockIdx.x * 4 + (threadIdx.x >> 6);
  if (node >= N) return;
  int lane = threadIdx.x & 63;
  int li = lane * 2;                 // li = head*32 + d; head = 16-lane group
  uint_t fdu = *(const uint_t*)&FD[(size_t)node*128 + li];
  float fd0 = bl(fdu), fd1 = bh(fdu);
  float a0 = attn[li], a1 = attn[li + 1];
  float acc0 = 0.f, acc1 = 0.f, den = 0.f;
  int beg = rowp[node], end = rowp[node + 1];   // deg >= 1 (self-loops)

  uint_t cur[4];
  #pragma unroll
  for (int j = 0; j < 4; ++j) {
    int idx = beg + j;
    int s = csrc[(idx < end) ? idx : (end - 1)];
    cur[j] = *(const uint_t*)&FS[(size_t)s*128 + li];
  }
  for (int kb = beg; kb < end; kb += 4) {
    uint_t nxt[4] = {0u, 0u, 0u, 0u};
    if (kb + 4 < end) {
      #pragma unroll
      for (int j = 0; j < 4; ++j) {
        int idx = kb + 4 + j;
        int s = csrc[(idx < end) ? idx : (end - 1)];
        nxt[j] = *(const uint_t*)&FS[(size_t)s*128 + li];
      }
    }
    #pragma unroll
    for (int j = 0; j < 4; ++j) {
      float c0 = bl(cur[j]), c1 = bh(cur[j]);
      float t0 = c0 + fd0; t0 = fmaxf(t0, 0.2f*t0);   // leaky_relu 0.2
      float t1 = c1 + fd1; t1 = fmaxf(t1, 0.2f*t1);
      float p = t0*a0 + t1*a1;
      p += __shfl_xor(p, 1);
      p += __shfl_xor(p, 2);
      p += __shfl_xor(p, 4);
      p += __shfl_xor(p, 8);         // per-head (16-lane) dot reduce
      float ex = (kb + j < end) ? __expf(p) : 0.f;    // logits O(1); tail masked
      den  += ex;
      acc0 += ex * c0;
      acc1 += ex * c1;
    }
    cur[0] = nxt[0]; cur[1] = nxt[1]; cur[2] = nxt[2]; cur[3] = nxt[3];
  }
  float rden = (den > 0.f) ? 1.f / den : 0.f;
  float o0 = acc0 * rden, o1 = acc1 * rden;
  float2 hv = *(const float2*)&H[(size_t)node*128 + li];
  float x0 = 2.f*hv.x + o0;          // h + (out + h)
  float x1 = 2.f*hv.y + o1;
  float s = x0 + x1;
  #pragma unroll
  for (int m = 1; m < 64; m <<= 1) s += __shfl_xor(s, m);
  float mean = s * (1.f/128.f);
  float d0 = x0 - mean, d1 = x1 - mean;
  float v = d0*d0 + d1*d1;
  #pragma unroll
  for (int m = 1; m < 64; m <<= 1) v += __shfl_xor(v, m);
  float rs = rsqrtf(v * (1.f/128.f) + 1e-5f);
  float y0 = fmaxf(d0*rs*lng[li]     + lnb[li],     0.f);
  float y1 = fmaxf(d1*rs*lng[li + 1] + lnb[li + 1], 0.f);
  float2 yo = make_float2(y0, y1);
  *(float2*)&H[(size_t)node*128 + li] = yo;
}

// ---------------- pooled mean partials ----------------
__global__ __launch_bounds__(128) void k_pool(const float* __restrict__ H,
                                              float* __restrict__ pooled, int N){
  int c = threadIdx.x;
  float s = 0.f;
  for (int r = blockIdx.x; r < N; r += gridDim.x) s += H[(size_t)r*128 + c];
  atomicAdd(&pooled[c], s);
}

// ---------------- final head ----------------
__global__ __launch_bounds__(256) void k_final(
    const float* __restrict__ gf, const float* __restrict__ pooled,
    const float* __restrict__ Wg, const float* __restrict__ bg,
    const float* __restrict__ Wf1, const float* __restrict__ bf1,
    const float* __restrict__ Wf2, const float* __restrict__ bf2v,
    float* __restrict__ out, float inv_n)
{
  __shared__ float comb[256];
  __shared__ float t1[128];
  int tid = threadIdx.x;
  if (tid < 128) {
    comb[tid] = pooled[tid] * inv_n;
  } else {
    int c = tid - 128;
    float s = bg[c];
    for (int k = 0; k < 32; ++k) s += gf[k] * Wg[k*128 + c];
    comb[128 + c] = s;
  }
  __syncthreads();
  if (tid < 128) {
    float s = bf1[tid];
    for (int k = 0; k < 256; ++k) s += comb[k] * Wf1[k*128 + tid];
    t1[tid] = fmaxf(s, 0.f);
  }
  __syncthreads();
  if (tid < 128) {
    float s = bf2v[tid];
    for (int k = 0; k < 128; ++k) s += t1[k] * Wf2[k*128 + tid];
    out[tid] = s;
  }
}

// ---------------- launch ----------------
extern "C" void kernel_launch(void* const* d_in, const int* in_sizes, int n_in,
                              void* d_out, int out_size, void* d_ws, size_t ws_size,
                              hipStream_t stream) {
  const float* node_feats = (const float*)d_in[0];
  const float* graph_feats= (const float*)d_in[1];
  const int*   src        = (const int*)d_in[2];
  const int*   dst        = (const int*)d_in[3];
  const float* W_in  = (const float*)d_in[4];
  const float* b_in  = (const float*)d_in[5];
  const float* W_g   = (const float*)d_in[6];
  const float* b_g   = (const float*)d_in[7];
  const float* W_src = (const float*)d_in[8];
  const float* b_src = (const float*)d_in[9];
  const float* W_dst = (const float*)d_in[10];
  const float* b_dst = (const float*)d_in[11];
  const float* attn  = (const float*)d_in[12];
  const float* ln_g  = (const float*)d_in[13];
  const float* ln_b  = (const float*)d_in[14];
  const float* W_f1  = (const float*)d_in[15];
  const float* b_f1  = (const float*)d_in[16];
  const float* W_f2  = (const float*)d_in[17];
  const float* b_f2  = (const float*)d_in[18];

  int N = in_sizes[0] / 64;
  int E = in_sizes[2];

  float* out_f = (float*)d_out;
  float* GEMB  = out_f;              // [128] graph_emb
  float* H     = out_f + 128;        // [N,128] output h doubles as working buffer

  // ws layout: [pooled f32 x128 | FS bf16 N*128 | FD bf16 N*128 | ints]
  float*    pooled = (float*)d_ws;
  ushort_t* FS = (ushort_t*)((char*)d_ws + 512);
  ushort_t* FD = FS + (size_t)N * 128;
  int* ibase = (int*)(FD + (size_t)N * 128);
  int* deg  = ibase;
  int* cnt  = ibase + N;
  int* rowp = ibase + 2*N;
  int* csrc = ibase + 3*N + 1;

  k_zero<<<(2*N + 255)/256, 256, 0, stream>>>(deg, 2*N);
  k_zero<<<1, 256, 0, stream>>>((int*)pooled, 128);

  k_hist<<<2048, 256, 0, stream>>>(dst, deg, E);
  k_scan<<<1, 1024, 0, stream>>>(deg, rowp, N);
  k_scatter<<<2048, 256, 0, stream>>>(src, dst, rowp, cnt, csrc, E);

  k_gemm_in<<<(N + 63)/64, 256, 0, stream>>>(node_feats, W_in, b_in, H, N);

  for (int l = 0; l < 3; ++l) {
    k_gemm_layer<<<(N + 63)/64, 256, 0, stream>>>(
        H, W_src + l*16384, W_dst + l*16384, b_src + l*128, b_dst + l*128,
        FS, FD, N);
    k_edge<<<(N + 3)/4, 256, 0, stream>>>(
        FS, FD, H, rowp, csrc,
        attn + l*128, ln_g + l*128, ln_b + l*128, N);
  }

  k_pool<<<512, 128, 0, stream>>>(H, pooled, N);
  k_final<<<1, 256, 0, stream>>>(graph_feats, pooled, W_g, b_g, W_f1, b_f1,
                                 W_f2, b_f2, GEMB, 1.0f / (float)N);
}

// Round 5
// 741.542 us; speedup vs baseline: 1.5266x; 1.1579x over previous
//
#include <hip/hip_runtime.h>

typedef unsigned short ushort_t;
typedef unsigned int   uint_t;
typedef __attribute__((ext_vector_type(8))) __bf16 bf16x8;
typedef __attribute__((ext_vector_type(4))) float   f32x4;

// bf16 helpers (stored bf16, computed f32)
__device__ __forceinline__ float bl(uint_t u){ return __uint_as_float(u<<16); }
__device__ __forceinline__ float bh(uint_t u){ return __uint_as_float(u & 0xffff0000u); }
__device__ __forceinline__ ushort_t f2b(float f){
  uint_t x = __float_as_uint(f);
  return (ushort_t)((x + 0x7fffu + ((x>>16)&1u)) >> 16);   // RTNE
}
__device__ __forceinline__ uint_t pack2(float a, float b){
  return (uint_t)f2b(a) | ((uint_t)f2b(b) << 16);
}

// ---------------- zeroing ----------------
__global__ void k_zero(int* __restrict__ p, int n){
  int i = blockIdx.x*256 + threadIdx.x;
  if (i < n) p[i] = 0;
}

// ---------------- CSR build ----------------
__global__ void k_hist(const int* __restrict__ dst, int* __restrict__ deg, int E){
  for (int i = blockIdx.x*blockDim.x + threadIdx.x; i < E; i += gridDim.x*blockDim.x)
    atomicAdd(&deg[dst[i]], 1);
}

__global__ __launch_bounds__(1024) void k_scan(const int* __restrict__ deg,
                                               int* __restrict__ rowp,
                                               int* __restrict__ pos, int n){
  __shared__ int sums[1024];
  int tid = threadIdx.x;
  int chunk = (n + 1023) >> 10;
  int start = tid * chunk;
  int end = start + chunk; if (end > n) end = n; if (start > n) start = n;
  int local = 0;
  for (int i = start; i < end; ++i) local += deg[i];
  sums[tid] = local;
  __syncthreads();
  for (int off = 1; off < 1024; off <<= 1) {
    int v = (tid >= off) ? sums[tid - off] : 0;
    __syncthreads();
    sums[tid] += v;
    __syncthreads();
  }
  int run = (tid == 0) ? 0 : sums[tid - 1];
  for (int i = start; i < end; ++i) { rowp[i] = run; pos[i] = run; run += deg[i]; }
  if (end == n) rowp[n] = run;
}

// scatter: fetch-add on pos (pre-seeded with rowp); 16-bit src indices
__global__ void k_scatter(const int* __restrict__ src, const int* __restrict__ dst,
                          int* __restrict__ pos, ushort_t* __restrict__ csrc, int E){
  for (int i = blockIdx.x*blockDim.x + threadIdx.x; i < E; i += gridDim.x*blockDim.x) {
    int d = dst[i];
    int p = atomicAdd(&pos[d], 1);
    csrc[p] = (ushort_t)src[i];
  }
}

// ------- input GEMM: H = nf @ W_in + b_in (f32), also writes HB (bf16) ------
__global__ __launch_bounds__(256) void k_gemm_in(
    const float* __restrict__ nf, const float* __restrict__ W,
    const float* __restrict__ b, float* __restrict__ H,
    ushort_t* __restrict__ HB, int N)
{
  __shared__ float sA[64*64];
  int row0 = blockIdx.x * 64;
  int tid = threadIdx.x;
  {
    int q = tid;
    #pragma unroll
    for (int j = 0; j < 4; ++j, q += 256) {
      int r = q >> 4;
      int c = (q & 15) << 2;
      float4 v = make_float4(0.f,0.f,0.f,0.f);
      if (row0 + r < N) v = *(const float4*)&nf[(size_t)(row0 + r)*64 + c];
      *(float4*)&sA[r*64 + c] = v;
    }
  }
  __syncthreads();
  int cg = tid & 15, rg = tid >> 4;
  int c0 = cg * 8;
  float acc[4][8];
  #pragma unroll
  for (int i = 0; i < 4; ++i)
    #pragma unroll
    for (int j = 0; j < 8; ++j) acc[i][j] = 0.f;
  for (int k = 0; k < 64; ++k) {
    float4 wa = *(const float4*)&W[k*128 + c0];
    float4 wb = *(const float4*)&W[k*128 + c0 + 4];
    float w[8] = {wa.x,wa.y,wa.z,wa.w,wb.x,wb.y,wb.z,wb.w};
    float hv[4];
    #pragma unroll
    for (int i = 0; i < 4; ++i) hv[i] = sA[(rg*4 + i)*64 + k];
    #pragma unroll
    for (int i = 0; i < 4; ++i)
      #pragma unroll
      for (int j = 0; j < 8; ++j) acc[i][j] += hv[i]*w[j];
  }
  float4 b1 = *(const float4*)&b[c0];
  float4 b2 = *(const float4*)&b[c0 + 4];
  float bb[8] = {b1.x,b1.y,b1.z,b1.w,b2.x,b2.y,b2.z,b2.w};
  #pragma unroll
  for (int i = 0; i < 4; ++i) {
    int row = row0 + rg*4 + i;
    if (row < N) {
      float o[8];
      #pragma unroll
      for (int j = 0; j < 8; ++j) o[j] = acc[i][j] + bb[j];
      *(float4*)&H[(size_t)row*128 + c0]     = make_float4(o[0],o[1],o[2],o[3]);
      *(float4*)&H[(size_t)row*128 + c0 + 4] = make_float4(o[4],o[5],o[6],o[7]);
      uint4 hb;
      hb.x = pack2(o[0],o[1]); hb.y = pack2(o[2],o[3]);
      hb.z = pack2(o[4],o[5]); hb.w = pack2(o[6],o[7]);
      *(uint4*)&HB[(size_t)row*128 + c0] = hb;
    }
  }
}

// ------- weight pre-swizzle into B-fragment order (bf16) ---------------------
// WB[l][ct][kc][lane][j]: value = Wcomb[k = kc*32 + (lane>>4)*8 + j][n = ct*16 + (lane&15)]
__global__ __launch_bounds__(256) void k_wswz(
    const float* __restrict__ Wsrc, const float* __restrict__ Wdst,
    ushort_t* __restrict__ WB)
{
  int t = blockIdx.x*256 + threadIdx.x;
  if (t >= 3*16*4*64) return;
  int l = t >> 12;
  int rem = t & 4095;
  int ct = rem >> 8;
  int kc = (rem >> 6) & 3;
  int lane = rem & 63;
  int n = ct*16 + (lane & 15);
  int kbase = kc*32 + (lane >> 4)*8;
  const float* Wp; int nn;
  if (n < 128) { Wp = Wsrc + l*16384; nn = n; }
  else         { Wp = Wdst + l*16384; nn = n - 128; }
  uint4 o;
  o.x = pack2(Wp[(kbase+0)*128+nn], Wp[(kbase+1)*128+nn]);
  o.y = pack2(Wp[(kbase+2)*128+nn], Wp[(kbase+3)*128+nn]);
  o.z = pack2(Wp[(kbase+4)*128+nn], Wp[(kbase+5)*128+nn]);
  o.w = pack2(Wp[(kbase+6)*128+nn], Wp[(kbase+7)*128+nn]);
  *(uint4*)&WB[(size_t)t * 8] = o;
}

// ------- layer GEMM via MFMA: FS/FD = bf16( HB @ Wcat + b ) ------------------
// block = 32 rows x 256 cols; 4 waves, wave w covers cols [w*64, w*64+64)
__global__ __launch_bounds__(256) void k_gemm_mfma(
    const ushort_t* __restrict__ HB, const ushort_t* __restrict__ WB,
    const float* __restrict__ bsrc, const float* __restrict__ bdst,
    ushort_t* __restrict__ FS, ushort_t* __restrict__ FD, int N)
{
  int m0 = blockIdx.x * 32;
  int tid = threadIdx.x;
  int w = tid >> 6, lane = tid & 63;
  int lrow = lane & 15, lk = lane >> 4;

  bf16x8 a[2][4];
  #pragma unroll
  for (int rt = 0; rt < 2; ++rt) {
    int row = m0 + rt*16 + lrow;
    if (row > N-1) row = N-1;                 // clamp; OOB rows masked at store
    #pragma unroll
    for (int kc = 0; kc < 4; ++kc)
      a[rt][kc] = *(const bf16x8*)&HB[(size_t)row*128 + kc*32 + lk*8];
  }

  #pragma unroll
  for (int c = 0; c < 4; ++c) {
    int ct = w*4 + c;
    int n = ct*16 + lrow;
    bf16x8 bfr[4];
    #pragma unroll
    for (int kc = 0; kc < 4; ++kc)
      bfr[kc] = *(const bf16x8*)&WB[((size_t)(ct*4 + kc)*64 + lane) * 8];
    float bias = (n < 128) ? bsrc[n] : bdst[n-128];
    ushort_t* OUT = (n < 128) ? FS : FD;
    int nn = n & 127;
    #pragma unroll
    for (int rt = 0; rt < 2; ++rt) {
      f32x4 acc = {0.f, 0.f, 0.f, 0.f};
      #pragma unroll
      for (int kc = 0; kc < 4; ++kc)
        acc = __builtin_amdgcn_mfma_f32_16x16x32_bf16(a[rt][kc], bfr[kc], acc, 0, 0, 0);
      #pragma unroll
      for (int reg = 0; reg < 4; ++reg) {
        int row = m0 + rt*16 + lk*4 + reg;    // C/D: col=lane&15, row=(lane>>4)*4+reg
        if (row < N) OUT[(size_t)row*128 + nn] = f2b(acc[reg] + bias);
      }
    }
  }
}

// ------- fused edge aggregate + softmax + residual + LN + ReLU ---------------
// 8-deep software pipeline over the gather loop.
__global__ __launch_bounds__(256) void k_edge(
    const ushort_t* __restrict__ FS, const ushort_t* __restrict__ FD,
    float* __restrict__ H, ushort_t* __restrict__ HB,
    const int* __restrict__ rowp, const ushort_t* __restrict__ csrc,
    const float* __restrict__ attn, const float* __restrict__ lng,
    const float* __restrict__ lnb, int N)
{
  int node = blockIdx.x * 4 + (threadIdx.x >> 6);
  if (node >= N) return;
  int lane = threadIdx.x & 63;
  int li = lane * 2;                 // li = head*32 + d; head = 16-lane group
  uint_t fdu = *(const uint_t*)&FD[(size_t)node*128 + li];
  float fd0 = bl(fdu), fd1 = bh(fdu);
  float a0 = attn[li], a1 = attn[li + 1];
  float acc0 = 0.f, acc1 = 0.f, den = 0.f;
  int beg = rowp[node], end = rowp[node + 1];   // deg >= 1 (self-loops)

  uint_t cur[8];
  #pragma unroll
  for (int j = 0; j < 8; ++j) {
    int idx = beg + j; if (idx > end - 1) idx = end - 1;
    int s = csrc[idx];
    cur[j] = *(const uint_t*)&FS[(size_t)s*128 + li];
  }
  for (int kb = beg; kb < end; kb += 8) {
    uint_t nxt[8] = {0u,0u,0u,0u,0u,0u,0u,0u};
    if (kb + 8 < end) {
      #pragma unroll
      for (int j = 0; j < 8; ++j) {
        int idx = kb + 8 + j; if (idx > end - 1) idx = end - 1;
        int s = csrc[idx];
        nxt[j] = *(const uint_t*)&FS[(size_t)s*128 + li];
      }
    }
    #pragma unroll
    for (int j = 0; j < 8; ++j) {
      float c0 = bl(cur[j]), c1 = bh(cur[j]);
      float t0 = c0 + fd0; t0 = fmaxf(t0, 0.2f*t0);   // leaky_relu 0.2
      float t1 = c1 + fd1; t1 = fmaxf(t1, 0.2f*t1);
      float p = t0*a0 + t1*a1;
      p += __shfl_xor(p, 1);
      p += __shfl_xor(p, 2);
      p += __shfl_xor(p, 4);
      p += __shfl_xor(p, 8);         // per-head (16-lane) dot reduce
      float ex = (kb + j < end) ? __expf(p) : 0.f;    // logits O(1); tail masked
      den  += ex;
      acc0 += ex * c0;
      acc1 += ex * c1;
      cur[j] = nxt[j];
    }
  }
  float rden = (den > 0.f) ? 1.f / den : 0.f;
  float o0 = acc0 * rden, o1 = acc1 * rden;
  float2 hv = *(const float2*)&H[(size_t)node*128 + li];
  float x0 = 2.f*hv.x + o0;          // h + (out + h)
  float x1 = 2.f*hv.y + o1;
  float s = x0 + x1;
  #pragma unroll
  for (int m = 1; m < 64; m <<= 1) s += __shfl_xor(s, m);
  float mean = s * (1.f/128.f);
  float d0 = x0 - mean, d1 = x1 - mean;
  float v = d0*d0 + d1*d1;
  #pragma unroll
  for (int m = 1; m < 64; m <<= 1) v += __shfl_xor(v, m);
  float rs = rsqrtf(v * (1.f/128.f) + 1e-5f);
  float y0 = fmaxf(d0*rs*lng[li]     + lnb[li],     0.f);
  float y1 = fmaxf(d1*rs*lng[li + 1] + lnb[li + 1], 0.f);
  *(float2*)&H[(size_t)node*128 + li] = make_float2(y0, y1);
  *(uint_t*)&HB[(size_t)node*128 + li] = pack2(y0, y1);
}

// ---------------- pooled mean partials ----------------
__global__ __launch_bounds__(128) void k_pool(const float* __restrict__ H,
                                              float* __restrict__ pooled, int N){
  int c = threadIdx.x;
  float s = 0.f;
  for (int r = blockIdx.x; r < N; r += gridDim.x) s += H[(size_t)r*128 + c];
  atomicAdd(&pooled[c], s);
}

// ---------------- final head ----------------
__global__ __launch_bounds__(256) void k_final(
    const float* __restrict__ gf, const float* __restrict__ pooled,
    const float* __restrict__ Wg, const float* __restrict__ bg,
    const float* __restrict__ Wf1, const float* __restrict__ bf1,
    const float* __restrict__ Wf2, const float* __restrict__ bf2v,
    float* __restrict__ out, float inv_n)
{
  __shared__ float comb[256];
  __shared__ float t1[128];
  int tid = threadIdx.x;
  if (tid < 128) {
    comb[tid] = pooled[tid] * inv_n;
  } else {
    int c = tid - 128;
    float s = bg[c];
    for (int k = 0; k < 32; ++k) s += gf[k] * Wg[k*128 + c];
    comb[128 + c] = s;
  }
  __syncthreads();
  if (tid < 128) {
    float s = bf1[tid];
    for (int k = 0; k < 256; ++k) s += comb[k] * Wf1[k*128 + tid];
    t1[tid] = fmaxf(s, 0.f);
  }
  __syncthreads();
  if (tid < 128) {
    float s = bf2v[tid];
    for (int k = 0; k < 128; ++k) s += t1[k] * Wf2[k*128 + tid];
    out[tid] = s;
  }
}

// ---------------- launch ----------------
extern "C" void kernel_launch(void* const* d_in, const int* in_sizes, int n_in,
                              void* d_out, int out_size, void* d_ws, size_t ws_size,
                              hipStream_t stream) {
  const float* node_feats = (const float*)d_in[0];
  const float* graph_feats= (const float*)d_in[1];
  const int*   src        = (const int*)d_in[2];
  const int*   dst        = (const int*)d_in[3];
  const float* W_in  = (const float*)d_in[4];
  const float* b_in  = (const float*)d_in[5];
  const float* W_g   = (const float*)d_in[6];
  const float* b_g   = (const float*)d_in[7];
  const float* W_src = (const float*)d_in[8];
  const float* b_src = (const float*)d_in[9];
  const float* W_dst = (const float*)d_in[10];
  const float* b_dst = (const float*)d_in[11];
  const float* attn  = (const float*)d_in[12];
  const float* ln_g  = (const float*)d_in[13];
  const float* ln_b  = (const float*)d_in[14];
  const float* W_f1  = (const float*)d_in[15];
  const float* b_f1  = (const float*)d_in[16];
  const float* W_f2  = (const float*)d_in[17];
  const float* b_f2  = (const float*)d_in[18];

  int N = in_sizes[0] / 64;
  int E = in_sizes[2];

  float* out_f = (float*)d_out;
  float* GEMB  = out_f;              // [128] graph_emb
  float* H     = out_f + 128;        // [N,128] output h doubles as working buffer

  // ws layout: pooled(512B) | FS | FD | HB (bf16 N*128 each) | WB | ints
  float*    pooled = (float*)d_ws;
  ushort_t* FS = (ushort_t*)((char*)d_ws + 512);
  ushort_t* FD = FS + (size_t)N * 128;
  ushort_t* HB = FD + (size_t)N * 128;
  ushort_t* WB = HB + (size_t)N * 128;         // 3*32768 elems
  int* ibase = (int*)(WB + 3*32768);
  int* deg  = ibase;                            // N
  int* pos  = ibase + N;                        // N
  int* rowp = ibase + 2*N;                      // N+1
  ushort_t* csrc = (ushort_t*)(ibase + 3*N + 1);// E

  k_zero<<<(N + 255)/256, 256, 0, stream>>>(deg, N);
  k_zero<<<1, 256, 0, stream>>>((int*)pooled, 128);

  k_wswz<<<(3*16*4*64 + 255)/256, 256, 0, stream>>>(W_src, W_dst, WB);
  k_hist<<<2048, 256, 0, stream>>>(dst, deg, E);
  k_scan<<<1, 1024, 0, stream>>>(deg, rowp, pos, N);
  k_scatter<<<2048, 256, 0, stream>>>(src, dst, pos, csrc, E);

  k_gemm_in<<<(N + 63)/64, 256, 0, stream>>>(node_feats, W_in, b_in, H, HB, N);

  for (int l = 0; l < 3; ++l) {
    k_gemm_mfma<<<(N + 31)/32, 256, 0, stream>>>(
        HB, WB + (size_t)l*32768, b_src + l*128, b_dst + l*128, FS, FD, N);
    k_edge<<<(N + 3)/4, 256, 0, stream>>>(
        FS, FD, H, HB, rowp, csrc,
        attn + l*128, ln_g + l*128, ln_b + l*128, N);
  }

  k_pool<<<512, 128, 0, stream>>>(H, pooled, N);
  k_final<<<1, 256, 0, stream>>>(graph_feats, pooled, W_g, b_g, W_f1, b_f1,
                                 W_f2, b_f2, GEMB, 1.0f / (float)N);
}

// Round 6
// 671.901 us; speedup vs baseline: 1.6848x; 1.1036x over previous
//
#include <hip/hip_runtime.h>

typedef unsigned short ushort_t;
typedef unsigned int   uint_t;
typedef __attribute__((ext_vector_type(8))) __bf16 bf16x8;
typedef __attribute__((ext_vector_type(4))) float   f32x4;

// bf16 helpers (stored bf16, computed f32)
__device__ __forceinline__ float bl(uint_t u){ return __uint_as_float(u<<16); }
__device__ __forceinline__ float bh(uint_t u){ return __uint_as_float(u & 0xffff0000u); }
__device__ __forceinline__ ushort_t f2b(float f){
  uint_t x = __float_as_uint(f);
  return (ushort_t)((x + 0x7fffu + ((x>>16)&1u)) >> 16);   // RTNE
}
__device__ __forceinline__ uint_t pack2(float a, float b){
  return (uint_t)f2b(a) | ((uint_t)f2b(b) << 16);
}

#define NBK 128          // max dst buckets (bucket = dst >> 9)
#define PBLK 256         // partition blocks

// ---------------- zeroing ----------------
__global__ void k_zero(int* __restrict__ p, int n){
  int i = blockIdx.x*256 + threadIdx.x;
  if (i < n) p[i] = 0;
}

// ------- CSR stage 1: per-node degree + per-(block,bucket) histogram --------
__global__ __launch_bounds__(256) void k_hist_bucket(
    const int* __restrict__ dst, int* __restrict__ deg,
    int* __restrict__ bhist, int E, int epb)
{
  __shared__ int lh[NBK];
  int blk = blockIdx.x, t = threadIdx.x;
  if (t < NBK) lh[t] = 0;
  __syncthreads();
  int s = blk*epb, e = s + epb; if (e > E) e = E;
  for (int i = s + t; i < e; i += 256) {
    int d = dst[i];
    atomicAdd(&deg[d], 1);
    atomicAdd(&lh[d >> 9], 1);
  }
  __syncthreads();
  if (t < NBK) bhist[t*PBLK + blk] = lh[t];   // bucket-major
}

// ------- CSR stage 2: scan (bucket,block) hist -> gOff; scan deg -> rowp ----
__global__ __launch_bounds__(1024) void k_scan2(
    const int* __restrict__ deg, const int* __restrict__ bhist,
    int* __restrict__ rowp, int* __restrict__ gOff,
    int* __restrict__ bucketOff, int n, int E)
{
  __shared__ int sums[1024];
  int tid = threadIdx.x;
  {  // scan bhist[NBK*PBLK = 32768], 32 per thread
    int s0 = tid * 32;
    int local = 0;
    #pragma unroll
    for (int i = 0; i < 32; ++i) local += bhist[s0 + i];
    sums[tid] = local;
    __syncthreads();
    for (int off = 1; off < 1024; off <<= 1) {
      int v = (tid >= off) ? sums[tid - off] : 0;
      __syncthreads();
      sums[tid] += v;
      __syncthreads();
    }
    int run = (tid == 0) ? 0 : sums[tid - 1];
    #pragma unroll
    for (int i = 0; i < 32; ++i) { gOff[s0 + i] = run; run += bhist[s0 + i]; }
  }
  __syncthreads();
  if (tid < NBK) bucketOff[tid] = gOff[tid*PBLK];
  if (tid == NBK) bucketOff[NBK] = E;
  __syncthreads();
  {  // scan deg[n] -> rowp
    int chunk = (n + 1023) >> 10;
    int start = tid * chunk;
    int end = start + chunk; if (end > n) end = n; if (start > n) start = n;
    int local = 0;
    for (int i = start; i < end; ++i) local += deg[i];
    sums[tid] = local;
    __syncthreads();
    for (int off = 1; off < 1024; off <<= 1) {
      int v = (tid >= off) ? sums[tid - off] : 0;
      __syncthreads();
      sums[tid] += v;
      __syncthreads();
    }
    int run = (tid == 0) ? 0 : sums[tid - 1];
    for (int i = start; i < end; ++i) { rowp[i] = run; run += deg[i]; }
    if (end == n) rowp[n] = run;
  }
}

// ------- CSR stage 3: partition edges into dst-buckets (localized writes) ---
__global__ __launch_bounds__(256) void k_part(
    const int* __restrict__ src, const int* __restrict__ dst,
    const int* __restrict__ gOff, uint_t* __restrict__ part, int E, int epb)
{
  __shared__ int loff[NBK];
  int blk = blockIdx.x, t = threadIdx.x;
  if (t < NBK) loff[t] = gOff[t*PBLK + blk];
  __syncthreads();
  int s = blk*epb, e = s + epb; if (e > E) e = E;
  for (int i = s + t; i < e; i += 256) {
    int d = dst[i];
    int b = d >> 9;
    int p = atomicAdd(&loff[b], 1);
    part[p] = (uint_t)src[i] | ((uint_t)(d & 511) << 16);
  }
}

// ------- CSR stage 4: within-bucket placement (contiguous csrc window) ------
__global__ __launch_bounds__(512) void k_csr(
    const uint_t* __restrict__ part, const int* __restrict__ bucketOff,
    const int* __restrict__ rowp, ushort_t* __restrict__ csrc, int N)
{
  __shared__ int lpos[512];
  int b = blockIdx.x, t = threadIdx.x;
  int base = b << 9;
  int cnt = N - base; if (cnt > 512) cnt = 512;
  if (t < cnt) lpos[t] = rowp[base + t];
  __syncthreads();
  int s = bucketOff[b], e = bucketOff[b + 1];
  for (int i = s + t; i < e; i += 512) {
    uint_t pr = part[i];
    int p = atomicAdd(&lpos[pr >> 16], 1);
    csrc[p] = (ushort_t)(pr & 0xffffu);
  }
}

// ------- input GEMM: H = nf @ W_in + b_in (f32), also writes HB (bf16) ------
__global__ __launch_bounds__(256) void k_gemm_in(
    const float* __restrict__ nf, const float* __restrict__ W,
    const float* __restrict__ b, float* __restrict__ H,
    ushort_t* __restrict__ HB, int N)
{
  __shared__ float sA[64*64];
  int row0 = blockIdx.x * 64;
  int tid = threadIdx.x;
  {
    int q = tid;
    #pragma unroll
    for (int j = 0; j < 4; ++j, q += 256) {
      int r = q >> 4;
      int c = (q & 15) << 2;
      float4 v = make_float4(0.f,0.f,0.f,0.f);
      if (row0 + r < N) v = *(const float4*)&nf[(size_t)(row0 + r)*64 + c];
      *(float4*)&sA[r*64 + c] = v;
    }
  }
  __syncthreads();
  int cg = tid & 15, rg = tid >> 4;
  int c0 = cg * 8;
  float acc[4][8];
  #pragma unroll
  for (int i = 0; i < 4; ++i)
    #pragma unroll
    for (int j = 0; j < 8; ++j) acc[i][j] = 0.f;
  for (int k = 0; k < 64; ++k) {
    float4 wa = *(const float4*)&W[k*128 + c0];
    float4 wb = *(const float4*)&W[k*128 + c0 + 4];
    float w[8] = {wa.x,wa.y,wa.z,wa.w,wb.x,wb.y,wb.z,wb.w};
    float hv[4];
    #pragma unroll
    for (int i = 0; i < 4; ++i) hv[i] = sA[(rg*4 + i)*64 + k];
    #pragma unroll
    for (int i = 0; i < 4; ++i)
      #pragma unroll
      for (int j = 0; j < 8; ++j) acc[i][j] += hv[i]*w[j];
  }
  float4 b1 = *(const float4*)&b[c0];
  float4 b2 = *(const float4*)&b[c0 + 4];
  float bb[8] = {b1.x,b1.y,b1.z,b1.w,b2.x,b2.y,b2.z,b2.w};
  #pragma unroll
  for (int i = 0; i < 4; ++i) {
    int row = row0 + rg*4 + i;
    if (row < N) {
      float o[8];
      #pragma unroll
      for (int j = 0; j < 8; ++j) o[j] = acc[i][j] + bb[j];
      *(float4*)&H[(size_t)row*128 + c0]     = make_float4(o[0],o[1],o[2],o[3]);
      *(float4*)&H[(size_t)row*128 + c0 + 4] = make_float4(o[4],o[5],o[6],o[7]);
      uint4 hb;
      hb.x = pack2(o[0],o[1]); hb.y = pack2(o[2],o[3]);
      hb.z = pack2(o[4],o[5]); hb.w = pack2(o[6],o[7]);
      *(uint4*)&HB[(size_t)row*128 + c0] = hb;
    }
  }
}

// ------- weight pre-swizzle into B-fragment order (bf16) ---------------------
__global__ __launch_bounds__(256) void k_wswz(
    const float* __restrict__ Wsrc, const float* __restrict__ Wdst,
    ushort_t* __restrict__ WB)
{
  int t = blockIdx.x*256 + threadIdx.x;
  if (t >= 3*16*4*64) return;
  int l = t >> 12;
  int rem = t & 4095;
  int ct = rem >> 8;
  int kc = (rem >> 6) & 3;
  int lane = rem & 63;
  int n = ct*16 + (lane & 15);
  int kbase = kc*32 + (lane >> 4)*8;
  const float* Wp; int nn;
  if (n < 128) { Wp = Wsrc + l*16384; nn = n; }
  else         { Wp = Wdst + l*16384; nn = n - 128; }
  uint4 o;
  o.x = pack2(Wp[(kbase+0)*128+nn], Wp[(kbase+1)*128+nn]);
  o.y = pack2(Wp[(kbase+2)*128+nn], Wp[(kbase+3)*128+nn]);
  o.z = pack2(Wp[(kbase+4)*128+nn], Wp[(kbase+5)*128+nn]);
  o.w = pack2(Wp[(kbase+6)*128+nn], Wp[(kbase+7)*128+nn]);
  *(uint4*)&WB[(size_t)t * 8] = o;
}

// ------- layer GEMM via MFMA: FS/FD = bf16( HB @ Wcat + b ) ------------------
__global__ __launch_bounds__(256) void k_gemm_mfma(
    const ushort_t* __restrict__ HB, const ushort_t* __restrict__ WB,
    const float* __restrict__ bsrc, const float* __restrict__ bdst,
    ushort_t* __restrict__ FS, ushort_t* __restrict__ FD, int N)
{
  int m0 = blockIdx.x * 32;
  int tid = threadIdx.x;
  int w = tid >> 6, lane = tid & 63;
  int lrow = lane & 15, lk = lane >> 4;

  bf16x8 a[2][4];
  #pragma unroll
  for (int rt = 0; rt < 2; ++rt) {
    int row = m0 + rt*16 + lrow;
    if (row > N-1) row = N-1;
    #pragma unroll
    for (int kc = 0; kc < 4; ++kc)
      a[rt][kc] = *(const bf16x8*)&HB[(size_t)row*128 + kc*32 + lk*8];
  }

  #pragma unroll
  for (int c = 0; c < 4; ++c) {
    int ct = w*4 + c;
    int n = ct*16 + lrow;
    bf16x8 bfr[4];
    #pragma unroll
    for (int kc = 0; kc < 4; ++kc)
      bfr[kc] = *(const bf16x8*)&WB[((size_t)(ct*4 + kc)*64 + lane) * 8];
    float bias = (n < 128) ? bsrc[n] : bdst[n-128];
    ushort_t* OUT = (n < 128) ? FS : FD;
    int nn = n & 127;
    #pragma unroll
    for (int rt = 0; rt < 2; ++rt) {
      f32x4 acc = {0.f, 0.f, 0.f, 0.f};
      #pragma unroll
      for (int kc = 0; kc < 4; ++kc)
        acc = __builtin_amdgcn_mfma_f32_16x16x32_bf16(a[rt][kc], bfr[kc], acc, 0, 0, 0);
      #pragma unroll
      for (int reg = 0; reg < 4; ++reg) {
        int row = m0 + rt*16 + lk*4 + reg;
        if (row < N) OUT[(size_t)row*128 + nn] = f2b(acc[reg] + bias);
      }
    }
  }
}

// ------- fused edge aggregate + softmax + residual + LN + ReLU ---------------
// 16-deep software pipeline over the gather loop.
__global__ __launch_bounds__(256) void k_edge(
    const ushort_t* __restrict__ FS, const ushort_t* __restrict__ FD,
    float* __restrict__ H, ushort_t* __restrict__ HB,
    const int* __restrict__ rowp, const ushort_t* __restrict__ csrc,
    const float* __restrict__ attn, const float* __restrict__ lng,
    const float* __restrict__ lnb, int N)
{
  int node = blockIdx.x * 4 + (threadIdx.x >> 6);
  if (node >= N) return;
  int lane = threadIdx.x & 63;
  int li = lane * 2;                 // li = head*32 + d; head = 16-lane group
  uint_t fdu = *(const uint_t*)&FD[(size_t)node*128 + li];
  float fd0 = bl(fdu), fd1 = bh(fdu);
  float a0 = attn[li], a1 = attn[li + 1];
  float acc0 = 0.f, acc1 = 0.f, den = 0.f;
  int beg = rowp[node], end = rowp[node + 1];   // deg >= 1 (self-loops)

  uint_t cur[16];
  #pragma unroll
  for (int j = 0; j < 16; ++j) {
    int idx = beg + j; if (idx > end - 1) idx = end - 1;
    int s = csrc[idx];
    cur[j] = *(const uint_t*)&FS[(size_t)s*128 + li];
  }
  for (int kb = beg; kb < end; kb += 16) {
    uint_t nxt[16];
    #pragma unroll
    for (int j = 0; j < 16; ++j) nxt[j] = 0u;
    if (kb + 16 < end) {
      #pragma unroll
      for (int j = 0; j < 16; ++j) {
        int idx = kb + 16 + j; if (idx > end - 1) idx = end - 1;
        int s = csrc[idx];
        nxt[j] = *(const uint_t*)&FS[(size_t)s*128 + li];
      }
    }
    #pragma unroll
    for (int j = 0; j < 16; ++j) {
      float c0 = bl(cur[j]), c1 = bh(cur[j]);
      float t0 = c0 + fd0; t0 = fmaxf(t0, 0.2f*t0);   // leaky_relu 0.2
      float t1 = c1 + fd1; t1 = fmaxf(t1, 0.2f*t1);
      float p = t0*a0 + t1*a1;
      p += __shfl_xor(p, 1);
      p += __shfl_xor(p, 2);
      p += __shfl_xor(p, 4);
      p += __shfl_xor(p, 8);         // per-head (16-lane) dot reduce
      float ex = (kb + j < end) ? __expf(p) : 0.f;    // logits O(1); tail masked
      den  += ex;
      acc0 += ex * c0;
      acc1 += ex * c1;
      cur[j] = nxt[j];
    }
  }
  float rden = (den > 0.f) ? 1.f / den : 0.f;
  float o0 = acc0 * rden, o1 = acc1 * rden;
  float2 hv = *(const float2*)&H[(size_t)node*128 + li];
  float x0 = 2.f*hv.x + o0;          // h + (out + h)
  float x1 = 2.f*hv.y + o1;
  float s = x0 + x1;
  #pragma unroll
  for (int m = 1; m < 64; m <<= 1) s += __shfl_xor(s, m);
  float mean = s * (1.f/128.f);
  float d0 = x0 - mean, d1 = x1 - mean;
  float v = d0*d0 + d1*d1;
  #pragma unroll
  for (int m = 1; m < 64; m <<= 1) v += __shfl_xor(v, m);
  float rs = rsqrtf(v * (1.f/128.f) + 1e-5f);
  float y0 = fmaxf(d0*rs*lng[li]     + lnb[li],     0.f);
  float y1 = fmaxf(d1*rs*lng[li + 1] + lnb[li + 1], 0.f);
  *(float2*)&H[(size_t)node*128 + li] = make_float2(y0, y1);
  *(uint_t*)&HB[(size_t)node*128 + li] = pack2(y0, y1);
}

// ---------------- pooled mean partials ----------------
__global__ __launch_bounds__(128) void k_pool(const float* __restrict__ H,
                                              float* __restrict__ pooled, int N){
  int c = threadIdx.x;
  float s = 0.f;
  for (int r = blockIdx.x; r < N; r += gridDim.x) s += H[(size_t)r*128 + c];
  atomicAdd(&pooled[c], s);
}

// ---------------- final head ----------------
__global__ __launch_bounds__(256) void k_final(
    const float* __restrict__ gf, const float* __restrict__ pooled,
    const float* __restrict__ Wg, const float* __restrict__ bg,
    const float* __restrict__ Wf1, const float* __restrict__ bf1,
    const float* __restrict__ Wf2, const float* __restrict__ bf2v,
    float* __restrict__ out, float inv_n)
{
  __shared__ float comb[256];
  __shared__ float t1[128];
  int tid = threadIdx.x;
  if (tid < 128) {
    comb[tid] = pooled[tid] * inv_n;
  } else {
    int c = tid - 128;
    float s = bg[c];
    for (int k = 0; k < 32; ++k) s += gf[k] * Wg[k*128 + c];
    comb[128 + c] = s;
  }
  __syncthreads();
  if (tid < 128) {
    float s = bf1[tid];
    for (int k = 0; k < 256; ++k) s += comb[k] * Wf1[k*128 + tid];
    t1[tid] = fmaxf(s, 0.f);
  }
  __syncthreads();
  if (tid < 128) {
    float s = bf2v[tid];
    for (int k = 0; k < 128; ++k) s += t1[k] * Wf2[k*128 + tid];
    out[tid] = s;
  }
}

// ---------------- launch ----------------
extern "C" void kernel_launch(void* const* d_in, const int* in_sizes, int n_in,
                              void* d_out, int out_size, void* d_ws, size_t ws_size,
                              hipStream_t stream) {
  const float* node_feats = (const float*)d_in[0];
  const float* graph_feats= (const float*)d_in[1];
  const int*   src        = (const int*)d_in[2];
  const int*   dst        = (const int*)d_in[3];
  const float* W_in  = (const float*)d_in[4];
  const float* b_in  = (const float*)d_in[5];
  const float* W_g   = (const float*)d_in[6];
  const float* b_g   = (const float*)d_in[7];
  const float* W_src = (const float*)d_in[8];
  const float* b_src = (const float*)d_in[9];
  const float* W_dst = (const float*)d_in[10];
  const float* b_dst = (const float*)d_in[11];
  const float* attn  = (const float*)d_in[12];
  const float* ln_g  = (const float*)d_in[13];
  const float* ln_b  = (const float*)d_in[14];
  const float* W_f1  = (const float*)d_in[15];
  const float* b_f1  = (const float*)d_in[16];
  const float* W_f2  = (const float*)d_in[17];
  const float* b_f2  = (const float*)d_in[18];

  int N = in_sizes[0] / 64;
  int E = in_sizes[2];

  float* out_f = (float*)d_out;
  float* GEMB  = out_f;              // [128] graph_emb
  float* H     = out_f + 128;        // [N,128] output h doubles as working buffer

  // ws layout: pooled | FS | FD | HB | WB | deg | rowp | bhist | gOff | bucketOff | csrc
  float*    pooled = (float*)d_ws;
  ushort_t* FS = (ushort_t*)((char*)d_ws + 512);
  ushort_t* FD = FS + (size_t)N * 128;
  ushort_t* HB = FD + (size_t)N * 128;
  ushort_t* WB = HB + (size_t)N * 128;          // 3*32768 elems
  int* ibase = (int*)(WB + 3*32768);
  int* deg       = ibase;                        // N
  int* rowp      = ibase + N;                    // N+1
  int* bhist     = ibase + 2*N + 1;              // NBK*PBLK
  int* gOff      = bhist + NBK*PBLK;             // NBK*PBLK
  int* bucketOff = gOff + NBK*PBLK;              // NBK+1
  ushort_t* csrc = (ushort_t*)(bucketOff + NBK + 1);  // E
  uint_t* part   = (uint_t*)FS;   // aliased: consumed before FS is written

  int epb = (E + PBLK - 1) / PBLK;
  int nb  = (N + 511) >> 9;

  k_zero<<<(N + 255)/256, 256, 0, stream>>>(deg, N);
  k_zero<<<1, 256, 0, stream>>>((int*)pooled, 128);

  k_wswz<<<(3*16*4*64 + 255)/256, 256, 0, stream>>>(W_src, W_dst, WB);
  k_hist_bucket<<<PBLK, 256, 0, stream>>>(dst, deg, bhist, E, epb);
  k_scan2<<<1, 1024, 0, stream>>>(deg, bhist, rowp, gOff, bucketOff, N, E);
  k_part<<<PBLK, 256, 0, stream>>>(src, dst, gOff, part, E, epb);
  k_csr<<<nb, 512, 0, stream>>>(part, bucketOff, rowp, csrc, N);

  k_gemm_in<<<(N + 63)/64, 256, 0, stream>>>(node_feats, W_in, b_in, H, HB, N);

  for (int l = 0; l < 3; ++l) {
    k_gemm_mfma<<<(N + 31)/32, 256, 0, stream>>>(
        HB, WB + (size_t)l*32768, b_src + l*128, b_dst + l*128, FS, FD, N);
    k_edge<<<(N + 3)/4, 256, 0, stream>>>(
        FS, FD, H, HB, rowp, csrc,
        attn + l*128, ln_g + l*128, ln_b + l*128, N);
  }

  k_pool<<<512, 128, 0, stream>>>(H, pooled, N);
  k_final<<<1, 256, 0, stream>>>(graph_feats, pooled, W_g, b_g, W_f1, b_f1,
                                 W_f2, b_f2, GEMB, 1.0f / (float)N);
}

// Round 7
// 618.214 us; speedup vs baseline: 1.8312x; 1.0868x over previous
//
#include <hip/hip_runtime.h>

typedef unsigned short ushort_t;
typedef unsigned int   uint_t;
typedef __attribute__((ext_vector_type(8))) __bf16 bf16x8;
typedef __attribute__((ext_vector_type(4))) float   f32x4;

// bf16 helpers (stored bf16, computed f32)
__device__ __forceinline__ float bl(uint_t u){ return __uint_as_float(u<<16); }
__device__ __forceinline__ float bh(uint_t u){ return __uint_as_float(u & 0xffff0000u); }
__device__ __forceinline__ ushort_t f2b(float f){
  uint_t x = __float_as_uint(f);
  return (ushort_t)((x + 0x7fffu + ((x>>16)&1u)) >> 16);   // RTNE
}
__device__ __forceinline__ uint_t pack2(float a, float b){
  return (uint_t)f2b(a) | ((uint_t)f2b(b) << 16);
}

#define NBK 128          // max dst buckets (bucket = dst >> 9)
#define PBLK 256         // partition blocks

// ---------------- zeroing ----------------
__global__ void k_zero(int* __restrict__ p, int n){
  int i = blockIdx.x*256 + threadIdx.x;
  if (i < n) p[i] = 0;
}

// ------- CSR stage 1: per-node degree + per-(block,bucket) histogram --------
__global__ __launch_bounds__(256) void k_hist_bucket(
    const int* __restrict__ dst, int* __restrict__ deg,
    int* __restrict__ bhist, int E, int epb)
{
  __shared__ int lh[NBK];
  int blk = blockIdx.x, t = threadIdx.x;
  if (t < NBK) lh[t] = 0;
  __syncthreads();
  int s = blk*epb, e = s + epb; if (e > E) e = E;
  for (int i = s + t; i < e; i += 256) {
    int d = dst[i];
    atomicAdd(&deg[d], 1);
    atomicAdd(&lh[d >> 9], 1);
  }
  __syncthreads();
  if (t < NBK) bhist[t*PBLK + blk] = lh[t];   // bucket-major
}

// ------- CSR stage 2: scan (bucket,block) hist -> gOff; scan deg -> rowp ----
__global__ __launch_bounds__(1024) void k_scan2(
    const int* __restrict__ deg, const int* __restrict__ bhist,
    int* __restrict__ rowp, int* __restrict__ gOff,
    int* __restrict__ bucketOff, int n, int E)
{
  __shared__ int sums[1024];
  int tid = threadIdx.x;
  {  // scan bhist[NBK*PBLK = 32768], 32 per thread
    int s0 = tid * 32;
    int local = 0;
    #pragma unroll
    for (int i = 0; i < 32; ++i) local += bhist[s0 + i];
    sums[tid] = local;
    __syncthreads();
    for (int off = 1; off < 1024; off <<= 1) {
      int v = (tid >= off) ? sums[tid - off] : 0;
      __syncthreads();
      sums[tid] += v;
      __syncthreads();
    }
    int run = (tid == 0) ? 0 : sums[tid - 1];
    #pragma unroll
    for (int i = 0; i < 32; ++i) { gOff[s0 + i] = run; run += bhist[s0 + i]; }
  }
  __syncthreads();
  if (tid < NBK) bucketOff[tid] = gOff[tid*PBLK];
  if (tid == NBK) bucketOff[NBK] = E;
  __syncthreads();
  {  // scan deg[n] -> rowp
    int chunk = (n + 1023) >> 10;
    int start = tid * chunk;
    int end = start + chunk; if (end > n) end = n; if (start > n) start = n;
    int local = 0;
    for (int i = start; i < end; ++i) local += deg[i];
    sums[tid] = local;
    __syncthreads();
    for (int off = 1; off < 1024; off <<= 1) {
      int v = (tid >= off) ? sums[tid - off] : 0;
      __syncthreads();
      sums[tid] += v;
      __syncthreads();
    }
    int run = (tid == 0) ? 0 : sums[tid - 1];
    for (int i = start; i < end; ++i) { rowp[i] = run; run += deg[i]; }
    if (end == n) rowp[n] = run;
  }
}

// ------- CSR stage 3: partition edges into dst-buckets (localized writes) ---
__global__ __launch_bounds__(256) void k_part(
    const int* __restrict__ src, const int* __restrict__ dst,
    const int* __restrict__ gOff, uint_t* __restrict__ part, int E, int epb)
{
  __shared__ int loff[NBK];
  int blk = blockIdx.x, t = threadIdx.x;
  if (t < NBK) loff[t] = gOff[t*PBLK + blk];
  __syncthreads();
  int s = blk*epb, e = s + epb; if (e > E) e = E;
  for (int i = s + t; i < e; i += 256) {
    int d = dst[i];
    int b = d >> 9;
    int p = atomicAdd(&loff[b], 1);
    part[p] = (uint_t)src[i] | ((uint_t)(d & 511) << 16);
  }
}

// ------- CSR stage 4: within-bucket placement; store src*256 (byte offset) --
__global__ __launch_bounds__(512) void k_csr(
    const uint_t* __restrict__ part, const int* __restrict__ bucketOff,
    const int* __restrict__ rowp, int* __restrict__ csrc32, int N)
{
  __shared__ int lpos[512];
  int b = blockIdx.x, t = threadIdx.x;
  int base = b << 9;
  int cnt = N - base; if (cnt > 512) cnt = 512;
  if (t < cnt) lpos[t] = rowp[base + t];
  __syncthreads();
  int s = bucketOff[b], e = bucketOff[b + 1];
  for (int i = s + t; i < e; i += 512) {
    uint_t pr = part[i];
    int p = atomicAdd(&lpos[pr >> 16], 1);
    csrc32[p] = (int)((pr & 0xffffu) << 8);   // byte offset of FS row
  }
}

// ------- input GEMM: H = nf @ W_in + b_in (f32), also writes HB (bf16) ------
__global__ __launch_bounds__(256) void k_gemm_in(
    const float* __restrict__ nf, const float* __restrict__ W,
    const float* __restrict__ b, float* __restrict__ H,
    ushort_t* __restrict__ HB, int N)
{
  __shared__ float sA[64*64];
  int row0 = blockIdx.x * 64;
  int tid = threadIdx.x;
  {
    int q = tid;
    #pragma unroll
    for (int j = 0; j < 4; ++j, q += 256) {
      int r = q >> 4;
      int c = (q & 15) << 2;
      float4 v = make_float4(0.f,0.f,0.f,0.f);
      if (row0 + r < N) v = *(const float4*)&nf[(size_t)(row0 + r)*64 + c];
      *(float4*)&sA[r*64 + c] = v;
    }
  }
  __syncthreads();
  int cg = tid & 15, rg = tid >> 4;
  int c0 = cg * 8;
  float acc[4][8];
  #pragma unroll
  for (int i = 0; i < 4; ++i)
    #pragma unroll
    for (int j = 0; j < 8; ++j) acc[i][j] = 0.f;
  for (int k = 0; k < 64; ++k) {
    float4 wa = *(const float4*)&W[k*128 + c0];
    float4 wb = *(const float4*)&W[k*128 + c0 + 4];
    float w[8] = {wa.x,wa.y,wa.z,wa.w,wb.x,wb.y,wb.z,wb.w};
    float hv[4];
    #pragma unroll
    for (int i = 0; i < 4; ++i) hv[i] = sA[(rg*4 + i)*64 + k];
    #pragma unroll
    for (int i = 0; i < 4; ++i)
      #pragma unroll
      for (int j = 0; j < 8; ++j) acc[i][j] += hv[i]*w[j];
  }
  float4 b1 = *(const float4*)&b[c0];
  float4 b2 = *(const float4*)&b[c0 + 4];
  float bb[8] = {b1.x,b1.y,b1.z,b1.w,b2.x,b2.y,b2.z,b2.w};
  #pragma unroll
  for (int i = 0; i < 4; ++i) {
    int row = row0 + rg*4 + i;
    if (row < N) {
      float o[8];
      #pragma unroll
      for (int j = 0; j < 8; ++j) o[j] = acc[i][j] + bb[j];
      *(float4*)&H[(size_t)row*128 + c0]     = make_float4(o[0],o[1],o[2],o[3]);
      *(float4*)&H[(size_t)row*128 + c0 + 4] = make_float4(o[4],o[5],o[6],o[7]);
      uint4 hb;
      hb.x = pack2(o[0],o[1]); hb.y = pack2(o[2],o[3]);
      hb.z = pack2(o[4],o[5]); hb.w = pack2(o[6],o[7]);
      *(uint4*)&HB[(size_t)row*128 + c0] = hb;
    }
  }
}

// ------- weight pre-swizzle into B-fragment order (bf16) ---------------------
__global__ __launch_bounds__(256) void k_wswz(
    const float* __restrict__ Wsrc, const float* __restrict__ Wdst,
    ushort_t* __restrict__ WB)
{
  int t = blockIdx.x*256 + threadIdx.x;
  if (t >= 3*16*4*64) return;
  int l = t >> 12;
  int rem = t & 4095;
  int ct = rem >> 8;
  int kc = (rem >> 6) & 3;
  int lane = rem & 63;
  int n = ct*16 + (lane & 15);
  int kbase = kc*32 + (lane >> 4)*8;
  const float* Wp; int nn;
  if (n < 128) { Wp = Wsrc + l*16384; nn = n; }
  else         { Wp = Wdst + l*16384; nn = n - 128; }
  uint4 o;
  o.x = pack2(Wp[(kbase+0)*128+nn], Wp[(kbase+1)*128+nn]);
  o.y = pack2(Wp[(kbase+2)*128+nn], Wp[(kbase+3)*128+nn]);
  o.z = pack2(Wp[(kbase+4)*128+nn], Wp[(kbase+5)*128+nn]);
  o.w = pack2(Wp[(kbase+6)*128+nn], Wp[(kbase+7)*128+nn]);
  *(uint4*)&WB[(size_t)t * 8] = o;
}

// ------- layer GEMM via MFMA: FS/FD = bf16( HB @ Wcat + b ) ------------------
__global__ __launch_bounds__(256) void k_gemm_mfma(
    const ushort_t* __restrict__ HB, const ushort_t* __restrict__ WB,
    const float* __restrict__ bsrc, const float* __restrict__ bdst,
    ushort_t* __restrict__ FS, ushort_t* __restrict__ FD, int N)
{
  int m0 = blockIdx.x * 32;
  int tid = threadIdx.x;
  int w = tid >> 6, lane = tid & 63;
  int lrow = lane & 15, lk = lane >> 4;

  bf16x8 a[2][4];
  #pragma unroll
  for (int rt = 0; rt < 2; ++rt) {
    int row = m0 + rt*16 + lrow;
    if (row > N-1) row = N-1;
    #pragma unroll
    for (int kc = 0; kc < 4; ++kc)
      a[rt][kc] = *(const bf16x8*)&HB[(size_t)row*128 + kc*32 + lk*8];
  }

  #pragma unroll
  for (int c = 0; c < 4; ++c) {
    int ct = w*4 + c;
    int n = ct*16 + lrow;
    bf16x8 bfr[4];
    #pragma unroll
    for (int kc = 0; kc < 4; ++kc)
      bfr[kc] = *(const bf16x8*)&WB[((size_t)(ct*4 + kc)*64 + lane) * 8];
    float bias = (n < 128) ? bsrc[n] : bdst[n-128];
    ushort_t* OUT = (n < 128) ? FS : FD;
    int nn = n & 127;
    #pragma unroll
    for (int rt = 0; rt < 2; ++rt) {
      f32x4 acc = {0.f, 0.f, 0.f, 0.f};
      #pragma unroll
      for (int kc = 0; kc < 4; ++kc)
        acc = __builtin_amdgcn_mfma_f32_16x16x32_bf16(a[rt][kc], bfr[kc], acc, 0, 0, 0);
      #pragma unroll
      for (int reg = 0; reg < 4; ++reg) {
        int row = m0 + rt*16 + lk*4 + reg;
        if (row < N) OUT[(size_t)row*128 + nn] = f2b(acc[reg] + bias);
      }
    }
  }
}

// ------- fused edge aggregate + softmax + residual + LN + ReLU ---------------
// Wave-uniform CSR indices (SALU), SGPR-base row gathers (zero per-edge vector
// address math), double-buffered depth-8 prefetch.
__global__ __launch_bounds__(256) void k_edge(
    const ushort_t* __restrict__ FS, const ushort_t* __restrict__ FD,
    float* __restrict__ H, ushort_t* __restrict__ HB,
    const int* __restrict__ rowp, const int* __restrict__ csrc32,
    const float* __restrict__ attn, const float* __restrict__ lng,
    const float* __restrict__ lnb, int N)
{
  int node = blockIdx.x * 4 + (threadIdx.x >> 6);
  node = __builtin_amdgcn_readfirstlane(node);
  if (node >= N) return;
  int lane = threadIdx.x & 63;
  int li = lane * 2;                 // li = head*32 + d; head = 16-lane group

  uint_t fdu = *(const uint_t*)((const char*)FD + node*256 + li*2);
  float fd0 = bl(fdu), fd1 = bh(fdu);
  float a0 = attn[li], a1 = attn[li + 1];
  float acc0 = 0.f, acc1 = 0.f, den = 0.f;
  int beg = __builtin_amdgcn_readfirstlane(rowp[node]);
  int end = __builtin_amdgcn_readfirstlane(rowp[node + 1]);   // deg >= 1
  int endm1 = end - 1;

  uint_t bufA[8], bufB[8];

  // prefetch block at kb into buf (clamped; SGPR row base, VGPR lane offset)
  #define PRE(buf, kb)                                                      \
    _Pragma("unroll")                                                       \
    for (int j = 0; j < 8; ++j) {                                           \
      int idx = (kb) + j; idx = (idx < endm1) ? idx : endm1;                \
      int soff = __builtin_amdgcn_readfirstlane(csrc32[idx]);               \
      (buf)[j] = *(const uint_t*)((const char*)FS + soff + (lane << 2));    \
    }

  #define PROC(buf, kb)                                                     \
    _Pragma("unroll")                                                       \
    for (int j = 0; j < 8; ++j) {                                           \
      float c0 = bl((buf)[j]), c1 = bh((buf)[j]);                           \
      float t0 = c0 + fd0; t0 = fmaxf(t0, 0.2f*t0);                         \
      float t1 = c1 + fd1; t1 = fmaxf(t1, 0.2f*t1);                         \
      float p = t0*a0 + t1*a1;                                              \
      p += __shfl_xor(p, 1);                                                \
      p += __shfl_xor(p, 2);                                                \
      p += __shfl_xor(p, 4);                                                \
      p += __shfl_xor(p, 8);                                                \
      float ex = ((kb) + j < end) ? __expf(p) : 0.f;                        \
      den  += ex;                                                           \
      acc0 += ex * c0;                                                      \
      acc1 += ex * c1;                                                      \
    }

  PRE(bufA, beg)
  int kb = beg;
  for (;;) {
    PRE(bufB, kb + 8)
    PROC(bufA, kb)
    kb += 8;
    if (kb >= end) break;
    PRE(bufA, kb + 8)
    PROC(bufB, kb)
    kb += 8;
    if (kb >= end) break;
  }
  #undef PRE
  #undef PROC

  float rden = (den > 0.f) ? 1.f / den : 0.f;
  float o0 = acc0 * rden, o1 = acc1 * rden;
  float2 hv = *(const float2*)((const char*)H + node*512 + li*4);
  float x0 = 2.f*hv.x + o0;          // h + (out + h)
  float x1 = 2.f*hv.y + o1;
  float s = x0 + x1;
  #pragma unroll
  for (int m = 1; m < 64; m <<= 1) s += __shfl_xor(s, m);
  float mean = s * (1.f/128.f);
  float d0 = x0 - mean, d1 = x1 - mean;
  float v = d0*d0 + d1*d1;
  #pragma unroll
  for (int m = 1; m < 64; m <<= 1) v += __shfl_xor(v, m);
  float rs = rsqrtf(v * (1.f/128.f) + 1e-5f);
  float y0 = fmaxf(d0*rs*lng[li]     + lnb[li],     0.f);
  float y1 = fmaxf(d1*rs*lng[li + 1] + lnb[li + 1], 0.f);
  *(float2*)((char*)H + node*512 + li*4) = make_float2(y0, y1);
  *(uint_t*)((char*)HB + node*256 + li*2) = pack2(y0, y1);
}

// ---------------- pooled mean partials ----------------
__global__ __launch_bounds__(128) void k_pool(const float* __restrict__ H,
                                              float* __restrict__ pooled, int N){
  int c = threadIdx.x;
  float s = 0.f;
  for (int r = blockIdx.x; r < N; r += gridDim.x) s += H[(size_t)r*128 + c];
  atomicAdd(&pooled[c], s);
}

// ---------------- final head ----------------
__global__ __launch_bounds__(256) void k_final(
    const float* __restrict__ gf, const float* __restrict__ pooled,
    const float* __restrict__ Wg, const float* __restrict__ bg,
    const float* __restrict__ Wf1, const float* __restrict__ bf1,
    const float* __restrict__ Wf2, const float* __restrict__ bf2v,
    float* __restrict__ out, float inv_n)
{
  __shared__ float comb[256];
  __shared__ float t1[128];
  int tid = threadIdx.x;
  if (tid < 128) {
    comb[tid] = pooled[tid] * inv_n;
  } else {
    int c = tid - 128;
    float s = bg[c];
    for (int k = 0; k < 32; ++k) s += gf[k] * Wg[k*128 + c];
    comb[128 + c] = s;
  }
  __syncthreads();
  if (tid < 128) {
    float s = bf1[tid];
    for (int k = 0; k < 256; ++k) s += comb[k] * Wf1[k*128 + tid];
    t1[tid] = fmaxf(s, 0.f);
  }
  __syncthreads();
  if (tid < 128) {
    float s = bf2v[tid];
    for (int k = 0; k < 128; ++k) s += t1[k] * Wf2[k*128 + tid];
    out[tid] = s;
  }
}

// ---------------- launch ----------------
extern "C" void kernel_launch(void* const* d_in, const int* in_sizes, int n_in,
                              void* d_out, int out_size, void* d_ws, size_t ws_size,
                              hipStream_t stream) {
  const float* node_feats = (const float*)d_in[0];
  const float* graph_feats= (const float*)d_in[1];
  const int*   src        = (const int*)d_in[2];
  const int*   dst        = (const int*)d_in[3];
  const float* W_in  = (const float*)d_in[4];
  const float* b_in  = (const float*)d_in[5];
  const float* W_g   = (const float*)d_in[6];
  const float* b_g   = (const float*)d_in[7];
  const float* W_src = (const float*)d_in[8];
  const float* b_src = (const float*)d_in[9];
  const float* W_dst = (const float*)d_in[10];
  const float* b_dst = (const float*)d_in[11];
  const float* attn  = (const float*)d_in[12];
  const float* ln_g  = (const float*)d_in[13];
  const float* ln_b  = (const float*)d_in[14];
  const float* W_f1  = (const float*)d_in[15];
  const float* b_f1  = (const float*)d_in[16];
  const float* W_f2  = (const float*)d_in[17];
  const float* b_f2  = (const float*)d_in[18];

  int N = in_sizes[0] / 64;
  int E = in_sizes[2];

  float* out_f = (float*)d_out;
  float* GEMB  = out_f;              // [128] graph_emb
  float* H     = out_f + 128;        // [N,128] output h doubles as working buffer

  // ws layout: pooled | FS | FD | HB | WB | deg | rowp | bhist | gOff | bucketOff | csrc32
  float*    pooled = (float*)d_ws;
  ushort_t* FS = (ushort_t*)((char*)d_ws + 512);
  ushort_t* FD = FS + (size_t)N * 128;
  ushort_t* HB = FD + (size_t)N * 128;
  ushort_t* WB = HB + (size_t)N * 128;          // 3*32768 elems
  int* ibase = (int*)(WB + 3*32768);
  int* deg       = ibase;                        // N
  int* rowp      = ibase + N;                    // N+1
  int* bhist     = ibase + 2*N + 1;              // NBK*PBLK
  int* gOff      = bhist + NBK*PBLK;             // NBK*PBLK
  int* bucketOff = gOff + NBK*PBLK;              // NBK+1
  int* csrc32    = bucketOff + NBK + 1;          // E
  uint_t* part   = (uint_t*)FS;   // aliased: consumed before FS is written

  int epb = (E + PBLK - 1) / PBLK;
  int nb  = (N + 511) >> 9;

  k_zero<<<(N + 255)/256, 256, 0, stream>>>(deg, N);
  k_zero<<<1, 256, 0, stream>>>((int*)pooled, 128);

  k_wswz<<<(3*16*4*64 + 255)/256, 256, 0, stream>>>(W_src, W_dst, WB);
  k_hist_bucket<<<PBLK, 256, 0, stream>>>(dst, deg, bhist, E, epb);
  k_scan2<<<1, 1024, 0, stream>>>(deg, bhist, rowp, gOff, bucketOff, N, E);
  k_part<<<PBLK, 256, 0, stream>>>(src, dst, gOff, part, E, epb);
  k_csr<<<nb, 512, 0, stream>>>(part, bucketOff, rowp, csrc32, N);

  k_gemm_in<<<(N + 63)/64, 256, 0, stream>>>(node_feats, W_in, b_in, H, HB, N);

  for (int l = 0; l < 3; ++l) {
    k_gemm_mfma<<<(N + 31)/32, 256, 0, stream>>>(
        HB, WB + (size_t)l*32768, b_src + l*128, b_dst + l*128, FS, FD, N);
    k_edge<<<(N + 3)/4, 256, 0, stream>>>(
        FS, FD, H, HB, rowp, csrc32,
        attn + l*128, ln_g + l*128, ln_b + l*128, N);
  }

  k_pool<<<512, 128, 0, stream>>>(H, pooled, N);
  k_final<<<1, 256, 0, stream>>>(graph_feats, pooled, W_g, b_g, W_f1, b_f1,
                                 W_f2, b_f2, GEMB, 1.0f / (float)N);
}

// Round 8
// 473.324 us; speedup vs baseline: 2.3917x; 1.3061x over previous
//
#include <hip/hip_runtime.h>

typedef unsigned short ushort_t;
typedef unsigned int   uint_t;
typedef __attribute__((ext_vector_type(8))) __bf16 bf16x8;
typedef __attribute__((ext_vector_type(4))) float   f32x4;

// bf16 helpers (stored bf16, computed f32)
__device__ __forceinline__ float bl(uint_t u){ return __uint_as_float(u<<16); }
__device__ __forceinline__ float bh(uint_t u){ return __uint_as_float(u & 0xffff0000u); }
__device__ __forceinline__ ushort_t f2b(float f){
  uint_t x = __float_as_uint(f);
  return (ushort_t)((x + 0x7fffu + ((x>>16)&1u)) >> 16);   // RTNE
}
__device__ __forceinline__ uint_t pack2(float a, float b){
  return (uint_t)f2b(a) | ((uint_t)f2b(b) << 16);
}

#define NBK 128          // max dst buckets (bucket = dst >> 9)
#define PBLK 256         // partition blocks

// ---------------- zeroing ----------------
__global__ void k_zero(int* __restrict__ p, int n){
  int i = blockIdx.x*256 + threadIdx.x;
  if (i < n) p[i] = 0;
}

// ------- CSR stage 1: per-(block,bucket) histogram (LDS only) ---------------
__global__ __launch_bounds__(256) void k_hist_bucket(
    const int* __restrict__ dst, int* __restrict__ bhist, int E, int epb)
{
  __shared__ int lh[NBK];
  int blk = blockIdx.x, t = threadIdx.x;
  if (t < NBK) lh[t] = 0;
  __syncthreads();
  int s = blk*epb, e = s + epb; if (e > E) e = E;
  for (int i = s + t; i < e; i += 256)
    atomicAdd(&lh[dst[i] >> 9], 1);
  __syncthreads();
  if (t < NBK) bhist[t*PBLK + blk] = lh[t];   // bucket-major
}

// ------- CSR stage 2: scan (bucket,block) hist -> gOff, bucketOff -----------
__global__ __launch_bounds__(1024) void k_scan2(
    const int* __restrict__ bhist, int* __restrict__ gOff,
    int* __restrict__ bucketOff, int E)
{
  __shared__ int sums[1024];
  int tid = threadIdx.x;
  int s0 = tid * 32;
  int local = 0;
  #pragma unroll
  for (int i = 0; i < 32; ++i) local += bhist[s0 + i];
  sums[tid] = local;
  __syncthreads();
  for (int off = 1; off < 1024; off <<= 1) {
    int v = (tid >= off) ? sums[tid - off] : 0;
    __syncthreads();
    sums[tid] += v;
    __syncthreads();
  }
  int run = (tid == 0) ? 0 : sums[tid - 1];
  #pragma unroll
  for (int i = 0; i < 32; ++i) { gOff[s0 + i] = run; run += bhist[s0 + i]; }
  __syncthreads();
  if (tid < NBK) bucketOff[tid] = gOff[tid*PBLK];
  if (tid == NBK) bucketOff[NBK] = E;
}

// ------- CSR stage 3: partition edges into dst-buckets (localized writes) ---
__global__ __launch_bounds__(256) void k_part(
    const int* __restrict__ src, const int* __restrict__ dst,
    const int* __restrict__ gOff, uint_t* __restrict__ part, int E, int epb)
{
  __shared__ int loff[NBK];
  int blk = blockIdx.x, t = threadIdx.x;
  if (t < NBK) loff[t] = gOff[t*PBLK + blk];
  __syncthreads();
  int s = blk*epb, e = s + epb; if (e > E) e = E;
  for (int i = s + t; i < e; i += 256) {
    int d = dst[i];
    int b = d >> 9;
    int p = atomicAdd(&loff[b], 1);
    part[p] = (uint_t)src[i] | ((uint_t)(d & 511) << 16);
  }
}

// ------- CSR stage 4: count+scan+rowp+place, all within bucket --------------
__global__ __launch_bounds__(512) void k_csr(
    const uint_t* __restrict__ part, const int* __restrict__ bucketOff,
    int* __restrict__ rowp, int* __restrict__ csrc32, int N, int E)
{
  __shared__ int lcnt[512];
  __shared__ int lpos[512];
  int b = blockIdx.x, t = threadIdx.x;
  int base = b << 9;
  int cnt = N - base; if (cnt > 512) cnt = 512;
  lcnt[t] = 0;
  __syncthreads();
  int s = bucketOff[b], e = bucketOff[b + 1];
  for (int i = s + t; i < e; i += 512)
    atomicAdd(&lcnt[part[i] >> 16], 1);
  __syncthreads();
  int v = lcnt[t];
  lpos[t] = v;
  __syncthreads();
  for (int off = 1; off < 512; off <<= 1) {       // inclusive scan
    int u = (t >= off) ? lpos[t - off] : 0;
    __syncthreads();
    lpos[t] += u;
    __syncthreads();
  }
  int rp = s + lpos[t] - v;                       // exclusive prefix + bucket base
  if (t < cnt) rowp[base + t] = rp;
  if (b == 0 && t == 0) rowp[N] = E;
  __syncthreads();
  lpos[t] = rp;
  __syncthreads();
  for (int i = s + t; i < e; i += 512) {
    uint_t pr = part[i];
    int p = atomicAdd(&lpos[pr >> 16], 1);
    csrc32[p] = (int)((pr & 0xffffu) << 8);       // byte offset of FS row
  }
}

// ------- input GEMM: HB = bf16( nf @ W_in + b_in ) --------------------------
__global__ __launch_bounds__(256) void k_gemm_in(
    const float* __restrict__ nf, const float* __restrict__ W,
    const float* __restrict__ b, ushort_t* __restrict__ HB, int N)
{
  __shared__ float sA[64*64];
  int row0 = blockIdx.x * 64;
  int tid = threadIdx.x;
  {
    int q = tid;
    #pragma unroll
    for (int j = 0; j < 4; ++j, q += 256) {
      int r = q >> 4;
      int c = (q & 15) << 2;
      float4 v = make_float4(0.f,0.f,0.f,0.f);
      if (row0 + r < N) v = *(const float4*)&nf[(size_t)(row0 + r)*64 + c];
      *(float4*)&sA[r*64 + c] = v;
    }
  }
  __syncthreads();
  int cg = tid & 15, rg = tid >> 4;
  int c0 = cg * 8;
  float acc[4][8];
  #pragma unroll
  for (int i = 0; i < 4; ++i)
    #pragma unroll
    for (int j = 0; j < 8; ++j) acc[i][j] = 0.f;
  for (int k = 0; k < 64; ++k) {
    float4 wa = *(const float4*)&W[k*128 + c0];
    float4 wb = *(const float4*)&W[k*128 + c0 + 4];
    float w[8] = {wa.x,wa.y,wa.z,wa.w,wb.x,wb.y,wb.z,wb.w};
    float hv[4];
    #pragma unroll
    for (int i = 0; i < 4; ++i) hv[i] = sA[(rg*4 + i)*64 + k];
    #pragma unroll
    for (int i = 0; i < 4; ++i)
      #pragma unroll
      for (int j = 0; j < 8; ++j) acc[i][j] += hv[i]*w[j];
  }
  float4 b1 = *(const float4*)&b[c0];
  float4 b2 = *(const float4*)&b[c0 + 4];
  float bb[8] = {b1.x,b1.y,b1.z,b1.w,b2.x,b2.y,b2.z,b2.w};
  #pragma unroll
  for (int i = 0; i < 4; ++i) {
    int row = row0 + rg*4 + i;
    if (row < N) {
      uint4 hb;
      hb.x = pack2(acc[i][0]+bb[0], acc[i][1]+bb[1]);
      hb.y = pack2(acc[i][2]+bb[2], acc[i][3]+bb[3]);
      hb.z = pack2(acc[i][4]+bb[4], acc[i][5]+bb[5]);
      hb.w = pack2(acc[i][6]+bb[6], acc[i][7]+bb[7]);
      *(uint4*)&HB[(size_t)row*128 + c0] = hb;
    }
  }
}

// ------- weight pre-swizzle into B-fragment order (bf16) ---------------------
__global__ __launch_bounds__(256) void k_wswz(
    const float* __restrict__ Wsrc, const float* __restrict__ Wdst,
    ushort_t* __restrict__ WB)
{
  int t = blockIdx.x*256 + threadIdx.x;
  if (t >= 3*16*4*64) return;
  int l = t >> 12;
  int rem = t & 4095;
  int ct = rem >> 8;
  int kc = (rem >> 6) & 3;
  int lane = rem & 63;
  int n = ct*16 + (lane & 15);
  int kbase = kc*32 + (lane >> 4)*8;
  const float* Wp; int nn;
  if (n < 128) { Wp = Wsrc + l*16384; nn = n; }
  else         { Wp = Wdst + l*16384; nn = n - 128; }
  uint4 o;
  o.x = pack2(Wp[(kbase+0)*128+nn], Wp[(kbase+1)*128+nn]);
  o.y = pack2(Wp[(kbase+2)*128+nn], Wp[(kbase+3)*128+nn]);
  o.z = pack2(Wp[(kbase+4)*128+nn], Wp[(kbase+5)*128+nn]);
  o.w = pack2(Wp[(kbase+6)*128+nn], Wp[(kbase+7)*128+nn]);
  *(uint4*)&WB[(size_t)t * 8] = o;
}

// ------- layer GEMM via MFMA: FS/FD = bf16( HB @ Wcat + b ) ------------------
__global__ __launch_bounds__(256) void k_gemm_mfma(
    const ushort_t* __restrict__ HB, const ushort_t* __restrict__ WB,
    const float* __restrict__ bsrc, const float* __restrict__ bdst,
    ushort_t* __restrict__ FS, ushort_t* __restrict__ FD, int N)
{
  int m0 = blockIdx.x * 32;
  int tid = threadIdx.x;
  int w = tid >> 6, lane = tid & 63;
  int lrow = lane & 15, lk = lane >> 4;

  bf16x8 a[2][4];
  #pragma unroll
  for (int rt = 0; rt < 2; ++rt) {
    int row = m0 + rt*16 + lrow;
    if (row > N-1) row = N-1;
    #pragma unroll
    for (int kc = 0; kc < 4; ++kc)
      a[rt][kc] = *(const bf16x8*)&HB[(size_t)row*128 + kc*32 + lk*8];
  }

  #pragma unroll
  for (int c = 0; c < 4; ++c) {
    int ct = w*4 + c;
    int n = ct*16 + lrow;
    bf16x8 bfr[4];
    #pragma unroll
    for (int kc = 0; kc < 4; ++kc)
      bfr[kc] = *(const bf16x8*)&WB[((size_t)(ct*4 + kc)*64 + lane) * 8];
    float bias = (n < 128) ? bsrc[n] : bdst[n-128];
    ushort_t* OUT = (n < 128) ? FS : FD;
    int nn = n & 127;
    #pragma unroll
    for (int rt = 0; rt < 2; ++rt) {
      f32x4 acc = {0.f, 0.f, 0.f, 0.f};
      #pragma unroll
      for (int kc = 0; kc < 4; ++kc)
        acc = __builtin_amdgcn_mfma_f32_16x16x32_bf16(a[rt][kc], bfr[kc], acc, 0, 0, 0);
      #pragma unroll
      for (int reg = 0; reg < 4; ++reg) {
        int row = m0 + rt*16 + lk*4 + reg;
        if (row < N) OUT[(size_t)row*128 + nn] = f2b(acc[reg] + bias);
      }
    }
  }
}

// ------- fused edge aggregate + softmax + residual + LN + ReLU ---------------
// Full-block main loop (no masks/clamps -> mergeable s_loads), prefetched tail,
// exp2 with prescaled attn, bf16 residual; f32 H written only on last layer.
__global__ __launch_bounds__(256) void k_edge(
    const ushort_t* __restrict__ FS, const ushort_t* __restrict__ FD,
    ushort_t* __restrict__ HB, float* __restrict__ H,
    const int* __restrict__ rowp, const int* __restrict__ csrc32,
    const float* __restrict__ attn, const float* __restrict__ lng,
    const float* __restrict__ lnb, int last, int N)
{
  int node = __builtin_amdgcn_readfirstlane(blockIdx.x * 4 + (threadIdx.x >> 6));
  if (node >= N) return;
  int lane = threadIdx.x & 63;
  int li = lane * 2;                 // li = head*32 + d; head = 16-lane group

  uint_t fdu = *(const uint_t*)((const char*)FD + node*256 + (lane << 2));
  float fd0 = bl(fdu), fd1 = bh(fdu);
  float a0 = attn[li]     * 1.44269504f;   // fold log2(e) into attn -> exp2
  float a1 = attn[li + 1] * 1.44269504f;
  float acc0 = 0.f, acc1 = 0.f, den = 0.f;
  int beg = __builtin_amdgcn_readfirstlane(rowp[node]);
  int end = __builtin_amdgcn_readfirstlane(rowp[node + 1]);   // deg >= 1
  int deg = end - beg;
  int nfull = deg >> 3, rem = deg & 7;
  int tb = beg + (nfull << 3);
  int endm1 = end - 1;

  uint_t bufA[8], bufB[8], bufT[8];

  #define PREF(buf, kb)                                                     \
    _Pragma("unroll")                                                       \
    for (int j = 0; j < 8; ++j) {                                           \
      int soff = csrc32[(kb) + j];                                          \
      (buf)[j] = *(const uint_t*)((const char*)FS + soff + (lane << 2));    \
    }

  #define PREFT(buf, kb)                                                   \
    _Pragma("unroll")                                                      \
    for (int j = 0; j < 8; ++j) {                                          \
      int idx = (kb) + j; idx = (idx < endm1) ? idx : endm1;               \
      int soff = csrc32[idx];                                              \
      (buf)[j] = *(const uint_t*)((const char*)FS + soff + (lane << 2));   \
    }

  #define EDGE_MATH(u, masked, j)                                          \
    {                                                                      \
      float c0 = bl(u), c1 = bh(u);                                        \
      float t0 = c0 + fd0; t0 = fmaxf(t0, 0.2f*t0);                        \
      float t1 = c1 + fd1; t1 = fmaxf(t1, 0.2f*t1);                        \
      float p = t0*a0 + t1*a1;                                             \
      p += __shfl_xor(p, 1);                                               \
      p += __shfl_xor(p, 2);                                               \
      p += __shfl_xor(p, 4);                                               \
      p += __shfl_xor(p, 8);                                               \
      float ex = __builtin_amdgcn_exp2f(p);                                \
      if (masked) ex = (j < rem) ? ex : 0.f;                               \
      den  += ex;                                                          \
      acc0 += ex * c0;                                                     \
      acc1 += ex * c1;                                                     \
    }

  #define PROCF(buf)                                                       \
    _Pragma("unroll")                                                      \
    for (int j = 0; j < 8; ++j) EDGE_MATH((buf)[j], 0, j)

  if (rem)   { PREFT(bufT, tb) }
  if (nfull) {
    PREF(bufA, beg)
    int remaining = nfull, kb = beg + 8;
    for (;;) {
      if (remaining > 1) { PREF(bufB, kb) }
      PROCF(bufA)
      if (--remaining == 0) break;
      kb += 8;
      if (remaining > 1) { PREF(bufA, kb) }
      PROCF(bufB)
      if (--remaining == 0) break;
      kb += 8;
    }
  }
  if (rem) {
    #pragma unroll
    for (int j = 0; j < 8; ++j) EDGE_MATH(bufT[j], 1, j)
  }
  #undef PREF
  #undef PREFT
  #undef EDGE_MATH
  #undef PROCF

  float rden = 1.f / den;            // deg >= 1 -> den > 0
  float o0 = acc0 * rden, o1 = acc1 * rden;
  uint_t hu = *(const uint_t*)((const char*)HB + node*256 + (lane << 2));
  float x0 = 2.f*bl(hu) + o0;        // h + (out + h)
  float x1 = 2.f*bh(hu) + o1;
  float s = x0 + x1;
  #pragma unroll
  for (int m = 1; m < 64; m <<= 1) s += __shfl_xor(s, m);
  float mean = s * (1.f/128.f);
  float d0 = x0 - mean, d1 = x1 - mean;
  float v = d0*d0 + d1*d1;
  #pragma unroll
  for (int m = 1; m < 64; m <<= 1) v += __shfl_xor(v, m);
  float rs = rsqrtf(v * (1.f/128.f) + 1e-5f);
  float y0 = fmaxf(d0*rs*lng[li]     + lnb[li],     0.f);
  float y1 = fmaxf(d1*rs*lng[li + 1] + lnb[li + 1], 0.f);
  if (last) {
    *(float2*)((char*)H + node*512 + (lane << 3)) = make_float2(y0, y1);
  } else {
    *(uint_t*)((char*)HB + node*256 + (lane << 2)) = pack2(y0, y1);
  }
}

// ---------------- pooled mean partials ----------------
__global__ __launch_bounds__(128) void k_pool(const float* __restrict__ H,
                                              float* __restrict__ pooled, int N){
  int c = threadIdx.x;
  float s = 0.f;
  for (int r = blockIdx.x; r < N; r += gridDim.x) s += H[(size_t)r*128 + c];
  atomicAdd(&pooled[c], s);
}

// ---------------- final head ----------------
__global__ __launch_bounds__(256) void k_final(
    const float* __restrict__ gf, const float* __restrict__ pooled,
    const float* __restrict__ Wg, const float* __restrict__ bg,
    const float* __restrict__ Wf1, const float* __restrict__ bf1,
    const float* __restrict__ Wf2, const float* __restrict__ bf2v,
    float* __restrict__ out, float inv_n)
{
  __shared__ float comb[256];
  __shared__ float t1[128];
  int tid = threadIdx.x;
  if (tid < 128) {
    comb[tid] = pooled[tid] * inv_n;
  } else {
    int c = tid - 128;
    float s = bg[c];
    for (int k = 0; k < 32; ++k) s += gf[k] * Wg[k*128 + c];
    comb[128 + c] = s;
  }
  __syncthreads();
  if (tid < 128) {
    float s = bf1[tid];
    for (int k = 0; k < 256; ++k) s += comb[k] * Wf1[k*128 + tid];
    t1[tid] = fmaxf(s, 0.f);
  }
  __syncthreads();
  if (tid < 128) {
    float s = bf2v[tid];
    for (int k = 0; k < 128; ++k) s += t1[k] * Wf2[k*128 + tid];
    out[tid] = s;
  }
}

// ---------------- launch ----------------
extern "C" void kernel_launch(void* const* d_in, const int* in_sizes, int n_in,
                              void* d_out, int out_size, void* d_ws, size_t ws_size,
                              hipStream_t stream) {
  const float* node_feats = (const float*)d_in[0];
  const float* graph_feats= (const float*)d_in[1];
  const int*   src        = (const int*)d_in[2];
  const int*   dst        = (const int*)d_in[3];
  const float* W_in  = (const float*)d_in[4];
  const float* b_in  = (const float*)d_in[5];
  const float* W_g   = (const float*)d_in[6];
  const float* b_g   = (const float*)d_in[7];
  const float* W_src = (const float*)d_in[8];
  const float* b_src = (const float*)d_in[9];
  const float* W_dst = (const float*)d_in[10];
  const float* b_dst = (const float*)d_in[11];
  const float* attn  = (const float*)d_in[12];
  const float* ln_g  = (const float*)d_in[13];
  const float* ln_b  = (const float*)d_in[14];
  const float* W_f1  = (const float*)d_in[15];
  const float* b_f1  = (const float*)d_in[16];
  const float* W_f2  = (const float*)d_in[17];
  const float* b_f2  = (const float*)d_in[18];

  int N = in_sizes[0] / 64;
  int E = in_sizes[2];

  float* out_f = (float*)d_out;
  float* GEMB  = out_f;              // [128] graph_emb
  float* H     = out_f + 128;        // [N,128] final h (written by last k_edge)

  // ws layout: pooled | FS | FD | HB | WB | rowp | bhist | gOff | bucketOff | csrc32
  float*    pooled = (float*)d_ws;
  ushort_t* FS = (ushort_t*)((char*)d_ws + 512);
  ushort_t* FD = FS + (size_t)N * 128;
  ushort_t* HB = FD + (size_t)N * 128;
  ushort_t* WB = HB + (size_t)N * 128;          // 3*32768 elems
  int* ibase = (int*)(WB + 3*32768);
  int* rowp      = ibase;                        // N+1
  int* bhist     = ibase + N + 1;                // NBK*PBLK
  int* gOff      = bhist + NBK*PBLK;             // NBK*PBLK
  int* bucketOff = gOff + NBK*PBLK;              // NBK+1
  int* csrc32    = bucketOff + NBK + 1;          // E
  uint_t* part   = (uint_t*)FS;   // aliased: consumed before FS is written

  int epb = (E + PBLK - 1) / PBLK;
  int nb  = (N + 511) >> 9;

  k_zero<<<1, 256, 0, stream>>>((int*)pooled, 128);

  k_wswz<<<(3*16*4*64 + 255)/256, 256, 0, stream>>>(W_src, W_dst, WB);
  k_hist_bucket<<<PBLK, 256, 0, stream>>>(dst, bhist, E, epb);
  k_scan2<<<1, 1024, 0, stream>>>(bhist, gOff, bucketOff, E);
  k_part<<<PBLK, 256, 0, stream>>>(src, dst, gOff, part, E, epb);
  k_csr<<<nb, 512, 0, stream>>>(part, bucketOff, rowp, csrc32, N, E);

  k_gemm_in<<<(N + 63)/64, 256, 0, stream>>>(node_feats, W_in, b_in, HB, N);

  for (int l = 0; l < 3; ++l) {
    k_gemm_mfma<<<(N + 31)/32, 256, 0, stream>>>(
        HB, WB + (size_t)l*32768, b_src + l*128, b_dst + l*128, FS, FD, N);
    k_edge<<<(N + 3)/4, 256, 0, stream>>>(
        FS, FD, HB, H, rowp, csrc32,
        attn + l*128, ln_g + l*128, ln_b + l*128, (l == 2) ? 1 : 0, N);
  }

  k_pool<<<512, 128, 0, stream>>>(H, pooled, N);
  k_final<<<1, 256, 0, stream>>>(graph_feats, pooled, W_g, b_g, W_f1, b_f1,
                                 W_f2, b_f2, GEMB, 1.0f / (float)N);
}